// Round 16
// baseline (191.886 us; speedup 1.0000x reference)
//
#include <hip/hip_runtime.h>
#include <cstdint>
#include <cstddef>

// ---------------------------------------------------------------------------
// AttnBlock, 5 dispatches:
//   prep:   GN 2-pass + wqk bf16 + W2=wp.wv + bpv (R15, proven)
//   qk:     gemm8 256x256  qkT = hT.wqk^T + bqk      (256 blocks, 1/CU)
//   scores: gemm8 256x256  E = exp(rsK*q.k) + rowsum (256 blocks)
//   vP:     gemm_nt<128>   vP = W2.hT^T + bpv        (512 blocks, proven)
//   PV':    gemm8 256x256  out = x + bp + vP.E^T/rowsum (128 blocks)
// gemm8 = 8-phase counted-vmcnt schedule (T3+T4): 8 waves (2Mx4N), BK=64,
// 128KB LDS dbuf, chunk-XOR swizzle, per-phase {ds_read quadrant | stage one
// 16KB cohort | vmcnt(4) | barrier | 16 MFMA setprio | barrier}.
// Cohort order [A-mf03, B-nf01, B-nf23, A-mf47] == consumption order; at each
// phase's vmcnt(4) the cohort needed by the NEXT phase has landed (2-cohort
// in-flight invariant, verified incl. prologue).
// Pinned lessons: BM256 (256,3) spills (R10); grids <= 1 round (R12);
// wave-uniform K-loop global reads serialize as s_loads (R13); GN needs
// explicit 2-pass float4 (R14).
// ---------------------------------------------------------------------------

typedef __bf16 bf16x8 __attribute__((ext_vector_type(8)));
typedef float f32x4 __attribute__((ext_vector_type(4)));

typedef __attribute__((address_space(1))) const void gl_void;
typedef __attribute__((address_space(3))) void lds_void;

#define GLD16(g, l)                                                     \
  __builtin_amdgcn_global_load_lds((gl_void*)(uintptr_t)(g),            \
                                   (lds_void*)(uintptr_t)(l), 16, 0, 0)

__device__ __forceinline__ unsigned short f2bf(float f) {
  unsigned int u = __builtin_bit_cast(unsigned int, f);
  u += 0x7fffu + ((u >> 16) & 1u);  // round-to-nearest-even
  return (unsigned short)(u >> 16);
}
__device__ __forceinline__ float bf2f(unsigned int h) {
  return __builtin_bit_cast(float, h << 16);
}

// ---- prep: W2 (0-127) + qk weights (128-1151) + GN 2-pass (1152-1663) -----
__global__ __launch_bounds__(256) void prep_kernel(
    const float* __restrict__ x, const float* __restrict__ gsc,
    const float* __restrict__ gbi, unsigned short* __restrict__ hT,
    const float* __restrict__ wq, const float* __restrict__ wk,
    const float* __restrict__ wv, const float* __restrict__ wp,
    const float* __restrict__ bq, const float* __restrict__ bk,
    const float* __restrict__ bv, unsigned short* __restrict__ oqk,
    unsigned short* __restrict__ W2o, float* __restrict__ bqk,
    float* __restrict__ bpv, float* __restrict__ rowsum) {
  const int t = threadIdx.x;
  if (blockIdx.x < 128) {  // ---- W2 = wp.wv (fp32), bpv = wp.bv ----
    __shared__ float swp[4][512];
    __shared__ float sbv[512];
    __shared__ float redp[4][4];
    const int o0 = blockIdx.x * 4;
#pragma unroll
    for (int r = 0; r < 4; ++r) {
      swp[r][t] = wp[(size_t)(o0 + r) * 512 + t];
      swp[r][256 + t] = wp[(size_t)(o0 + r) * 512 + 256 + t];
    }
    sbv[t] = bv[t];
    sbv[256 + t] = bv[256 + t];
    __syncthreads();
    float a0[4] = {}, a1[4] = {};
    for (int c = 0; c < 512; ++c) {
      const float v0 = wv[(size_t)c * 512 + t];
      const float v1 = wv[(size_t)c * 512 + 256 + t];
#pragma unroll
      for (int r = 0; r < 4; ++r) {
        a0[r] = fmaf(swp[r][c], v0, a0[r]);
        a1[r] = fmaf(swp[r][c], v1, a1[r]);
      }
    }
#pragma unroll
    for (int r = 0; r < 4; ++r) {
      W2o[(size_t)(o0 + r) * 512 + t] = f2bf(a0[r]);
      W2o[(size_t)(o0 + r) * 512 + 256 + t] = f2bf(a1[r]);
    }
    float s[4];
#pragma unroll
    for (int r = 0; r < 4; ++r)
      s[r] = swp[r][t] * sbv[t] + swp[r][256 + t] * sbv[256 + t];
#pragma unroll
    for (int r = 0; r < 4; ++r)
#pragma unroll
      for (int off = 32; off > 0; off >>= 1) s[r] += __shfl_down(s[r], off);
    if ((t & 63) == 0) {
#pragma unroll
      for (int r = 0; r < 4; ++r) redp[r][t >> 6] = s[r];
    }
    __syncthreads();
    if (t == 0) {
#pragma unroll
      for (int r = 0; r < 4; ++r)
        bpv[o0 + r] = redp[r][0] + redp[r][1] + redp[r][2] + redp[r][3];
    }
    return;
  }
  if (blockIdx.x < 1152) {  // ---- qk weights fp32 -> bf16, bias, rowsum ----
    const int idx = (blockIdx.x - 128) * 256 + t;
    oqk[idx] = f2bf(wq[idx]);
    oqk[262144 + idx] = f2bf(wk[idx]);
    if (idx < 1024) bqk[idx] = idx < 512 ? bq[idx] : bk[idx - 512];
    if (idx < 16384) rowsum[idx] = 0.f;
    return;
  }
  // ---- GroupNorm -> hT[b][i][c] bf16, explicit 2-pass, float4 both ----
  __shared__ float red[2][4];
  const int gb = blockIdx.x - 1152;
  const int b = gb >> 5;
  const int g = gb & 31;
  const int wid = t >> 6, lane = t & 63;
  const float* xp = x + ((size_t)(b * 512 + g * 16)) * 1024;

  float s = 0.f, s2 = 0.f;
#pragma unroll
  for (int c = 0; c < 16; ++c) {
    const float4 v = ((const float4*)(xp + (size_t)c * 1024))[t];
    s += (v.x + v.y) + (v.z + v.w);
    s2 += (v.x * v.x + v.y * v.y) + (v.z * v.z + v.w * v.w);
  }
#pragma unroll
  for (int off = 32; off > 0; off >>= 1) {
    s += __shfl_down(s, off);
    s2 += __shfl_down(s2, off);
  }
  if (lane == 0) { red[0][wid] = s; red[1][wid] = s2; }
  __syncthreads();
  const float S = red[0][0] + red[0][1] + red[0][2] + red[0][3];
  const float S2 = red[1][0] + red[1][1] + red[1][2] + red[1][3];
  const float mean = S * (1.f / 16384.f);
  const float var = S2 * (1.f / 16384.f) - mean * mean;
  const float rstd = rsqrtf(var + 1e-6f);

  float sc[16], bi[16];
#pragma unroll
  for (int c = 0; c < 16; ++c) {
    sc[c] = gsc[g * 16 + c] * rstd;
    bi[c] = gbi[g * 16 + c] - mean * sc[c];
  }
  unsigned short* hp = hT + (size_t)b * 1024 * 512 + g * 16;
#pragma unroll
  for (int half = 0; half < 2; ++half) {
    float4 r4[8];
#pragma unroll
    for (int c = 0; c < 8; ++c)
      r4[c] = ((const float4*)(xp + (size_t)(half * 8 + c) * 1024))[t];
#pragma unroll
    for (int ii = 0; ii < 4; ++ii) {
      const int i = 4 * t + ii;
      unsigned int pk[4];
#pragma unroll
      for (int p = 0; p < 4; ++p) {
        const int c0 = half * 8 + 2 * p;
        float e0, e1;
        if (ii == 0) { e0 = r4[2 * p].x; e1 = r4[2 * p + 1].x; }
        else if (ii == 1) { e0 = r4[2 * p].y; e1 = r4[2 * p + 1].y; }
        else if (ii == 2) { e0 = r4[2 * p].z; e1 = r4[2 * p + 1].z; }
        else { e0 = r4[2 * p].w; e1 = r4[2 * p + 1].w; }
        const float v0 = e0 * sc[c0] + bi[c0];
        const float v1 = e1 * sc[c0 + 1] + bi[c0 + 1];
        pk[p] = (unsigned int)f2bf(v0) | ((unsigned int)f2bf(v1) << 16);
      }
      *(uint4*)(hp + (size_t)i * 512 + half * 8) =
          make_uint4(pk[0], pk[1], pk[2], pk[3]);
    }
  }
}

// ------------------------- GEMM argument block -----------------------------
struct GArgs {
  const unsigned short *A, *B;
  void* Out;
  const float *bias, *resid;
  float* rowsum;
  long long sBb, sOb;
  int lda, ldb, ldo, btshift, obf, csplit, K, bmode, nx, nwg, epi;
  float scale;
};

// ------------------ old 2-phase engine (vP only, proven) -------------------
template <int BM>
__global__ __launch_bounds__(256, (BM == 256 ? 2 : 3)) void gemm_nt(
    GArgs g0, GArgs g1, int split) {
  constexpr int MF = BM / 32;
  constexpr int WMS = BM / 2;
  constexpr int ASLABS = BM / 32;
  constexpr int BOFF = BM * 128;
  __shared__ char lds[BM * 128 + 16384];

  const bool r1 = (int)blockIdx.x >= split;
  const GArgs g = r1 ? g1 : g0;
  const int lid = blockIdx.x - (r1 ? split : 0);

  const int cpx = g.nwg >> 3;
  const int rid = (lid & 7) * cpx + (lid >> 3);
  const int bx = rid % g.nx, by = rid / g.nx;
  const int m0 = by * BM, n0 = bx * 128;

  const int t = threadIdx.x;
  const int wid = t >> 6, lane = t & 63;
  const int srow = t >> 3;
  const int schunk = ((t & 7) ^ (srow & 7)) * 8;
  const unsigned short* gA = g.A + (size_t)(m0 + srow) * g.lda + schunk;
  const unsigned short* gB =
      g.B + (g.btshift ? (size_t)(m0 >> g.btshift) * g.sBb : 0) +
      (size_t)(n0 + srow) * g.ldb + schunk;
  const int stgO = wid << 10;

  f32x4 acc[MF][4] = {};
  const int wm = wid >> 1, wn = wid & 1;
  const int fr = lane & 15;
  const int slot0 = (((lane >> 4) ^ (fr & 7)) << 4);
  const int aoff = (wm * WMS + fr) * 128 + slot0;
  const int boff = BOFF + (wn * 64 + fr) * 128 + slot0;

  const int nt = g.K >> 6;
  for (int tt = 0; tt < nt; ++tt) {
    const size_t ko = (size_t)tt * 64;
#pragma unroll
    for (int c = 0; c < ASLABS; ++c)
      GLD16(gA + ko + (size_t)(c * 32) * g.lda, lds + c * 4096 + stgO);
#pragma unroll
    for (int c = 0; c < 4; ++c)
      GLD16(gB + ko + (size_t)(c * 32) * g.ldb, lds + BOFF + c * 4096 + stgO);
    __syncthreads();
#pragma unroll
    for (int kk = 0; kk < 2; ++kk) {
      const int kx = kk ? 64 : 0;
      bf16x8 av[MF], bv[4];
#pragma unroll
      for (int mf = 0; mf < MF; ++mf)
        av[mf] = *(const bf16x8*)(lds + ((aoff + mf * 2048) ^ kx));
#pragma unroll
      for (int nf = 0; nf < 4; ++nf)
        bv[nf] = *(const bf16x8*)(lds + ((boff + nf * 2048) ^ kx));
      __builtin_amdgcn_s_setprio(1);
#pragma unroll
      for (int mf = 0; mf < MF; ++mf)
#pragma unroll
        for (int nf = 0; nf < 4; ++nf)
          acc[mf][nf] = __builtin_amdgcn_mfma_f32_16x16x32_bf16(
              av[mf], bv[nf], acc[mf][nf], 0, 0, 0);
      __builtin_amdgcn_s_setprio(0);
    }
    __syncthreads();
  }

  const int em = m0 + wm * WMS + (lane >> 4) * 4;
  const int en = n0 + wn * 64 + fr;
#pragma unroll
  for (int mf = 0; mf < MF; ++mf) {
#pragma unroll
    for (int r = 0; r < 4; ++r) {
      const int gm = em + mf * 16 + r;
#pragma unroll
      for (int nf = 0; nf < 4; ++nf) {
        const int gn = en + nf * 16;
        float v = acc[mf][nf][r] * g.scale;
        if (g.bmode == 1) v += g.bias[gm];
        else if (g.bmode == 2) v += g.bias[gn];
        size_t off;
        if (g.csplit)
          off = (size_t)(gn >> 10) * g.sOb + (size_t)gm * g.ldo + (gn & 1023);
        else
          off = (size_t)gm * g.ldo + gn;
        if (g.resid) v += g.resid[off];
        if (g.obf) ((unsigned short*)g.Out)[off] = f2bf(v);
        else ((float*)g.Out)[off] = v;
      }
    }
  }
}

// --------------------- 8-phase 256x256 engine (gemm8) ----------------------
// 512 thr = 8 waves (wm=wid>>2, wn=wid&3); wave out 128x64; acc[8][4].
// LDS 2 x 64KB buffers: A[256 rows x 128B] @0, B @32768. Chunk-XOR swizzle.
__global__ __launch_bounds__(512, 2) void gemm8(GArgs g) {
  __shared__ char lds[131072];

  const int cpx = g.nwg >> 3;
  const int lid = blockIdx.x;
  const int rid = (lid & 7) * cpx + (lid >> 3);
  const int bx = rid % g.nx, by = rid / g.nx;
  const int m0 = by * 256, n0 = bx * 256;

  const int t = threadIdx.x;
  const int wid = t >> 6, lane = t & 63;
  const unsigned short* Ab = g.A;
  const unsigned short* Bb =
      g.B + (g.btshift ? (size_t)(m0 >> g.btshift) * g.sBb : 0);

  // ---- staging lambdas: one cohort = 16KB = 2 GLD16/thread ----
  const int l8 = lane >> 3;   // row within wave's 8-row slab
  const int l7 = lane & 7;    // chunk slot
  auto stA = [&](int half, char* dbuf, int ko) {  // A rows half*64+{0..63,128..191}
#pragma unroll
    for (int c = 0; c < 2; ++c) {
      const int rb = half * 64 + c * 128 + wid * 8;  // wave-uniform row base
      const int row = rb + l8;
      const int ch = ((l7 ^ (row & 7)) << 3);
      GLD16(Ab + (size_t)(m0 + row) * g.lda + ko + ch, dbuf + rb * 128);
    }
  };
  auto stB = [&](int half, char* dbuf, int ko) {  // B nf01/nf23 halves
#pragma unroll
    for (int c = 0; c < 2; ++c) {
      const int wb = (wid < 4) ? wid * 8 : (wid - 4) * 8 + 64;
      const int rb = wb + half * 32 + c * 128;       // wave-uniform row base
      const int row = rb + l8;
      const int ch = ((l7 ^ (row & 7)) << 3);
      GLD16(Bb + (size_t)(n0 + row) * g.ldb + ko + ch,
            dbuf + 32768 + rb * 128);
    }
  };

  // ---- fragment read setup ----
  const int wm = wid >> 2, wn = wid & 3;
  const int fr = lane & 15;
  const int slot0 = (((lane >> 4) ^ (fr & 7)) << 4);
  const int aB = (wm * 128 + fr) * 128 + slot0;          // mf adds 2048
  const int bB = 32768 + (wn * 64 + fr) * 128 + slot0;   // nf adds 2048

  f32x4 acc[8][4] = {};
  bf16x8 av[4][2], bv0[2][2], bv1[2][2];

  const int nT = g.K >> 6;
  // prologue: stage tile 0 cohorts in consumption order
  stA(0, lds, 0);
  stB(0, lds, 0);
  stB(1, lds, 0);
  stA(1, lds, 0);
  asm volatile("s_waitcnt vmcnt(4)" ::: "memory");  // C0,C1 landed
  __builtin_amdgcn_s_barrier();

  for (int T = 0; T < nT; ++T) {
    char* cb = lds + (T & 1) * 65536;
    char* nb = lds + ((T + 1) & 1) * 65536;
    const int ko = (T + 1) * 64;
    const bool st = (T + 1 < nT);

    // ---- phase 0: quadrant mf0-3 x nf0-1 ----
#pragma unroll
    for (int mf = 0; mf < 4; ++mf)
#pragma unroll
      for (int kk = 0; kk < 2; ++kk)
        av[mf][kk] = *(const bf16x8*)(cb + ((aB + mf * 2048) ^ (kk * 64)));
#pragma unroll
    for (int nf = 0; nf < 2; ++nf)
#pragma unroll
      for (int kk = 0; kk < 2; ++kk)
        bv0[nf][kk] = *(const bf16x8*)(cb + ((bB + nf * 2048) ^ (kk * 64)));
    if (st) stA(0, nb, ko);
    asm volatile("s_waitcnt vmcnt(4)" ::: "memory");
    __builtin_amdgcn_s_barrier();
    __builtin_amdgcn_s_setprio(1);
#pragma unroll
    for (int mf = 0; mf < 4; ++mf)
#pragma unroll
      for (int nf = 0; nf < 2; ++nf)
#pragma unroll
        for (int kk = 0; kk < 2; ++kk)
          acc[mf][nf] = __builtin_amdgcn_mfma_f32_16x16x32_bf16(
              av[mf][kk], bv0[nf][kk], acc[mf][nf], 0, 0, 0);
    __builtin_amdgcn_s_setprio(0);
    __builtin_amdgcn_s_barrier();

    // ---- phase 1: quadrant mf0-3 x nf2-3 ----
#pragma unroll
    for (int nf = 0; nf < 2; ++nf)
#pragma unroll
      for (int kk = 0; kk < 2; ++kk)
        bv1[nf][kk] =
            *(const bf16x8*)(cb + ((bB + (nf + 2) * 2048) ^ (kk * 64)));
    if (st) stB(0, nb, ko);
    asm volatile("s_waitcnt vmcnt(4)" ::: "memory");
    __builtin_amdgcn_s_barrier();
    __builtin_amdgcn_s_setprio(1);
#pragma unroll
    for (int mf = 0; mf < 4; ++mf)
#pragma unroll
      for (int nf = 0; nf < 2; ++nf)
#pragma unroll
        for (int kk = 0; kk < 2; ++kk)
          acc[mf][nf + 2] = __builtin_amdgcn_mfma_f32_16x16x32_bf16(
              av[mf][kk], bv1[nf][kk], acc[mf][nf + 2], 0, 0, 0);
    __builtin_amdgcn_s_setprio(0);
    __builtin_amdgcn_s_barrier();

    // ---- phase 2: quadrant mf4-7 x nf0-1 ----
#pragma unroll
    for (int mf = 0; mf < 4; ++mf)
#pragma unroll
      for (int kk = 0; kk < 2; ++kk)
        av[mf][kk] =
            *(const bf16x8*)(cb + ((aB + (mf + 4) * 2048) ^ (kk * 64)));
    if (st) stB(1, nb, ko);
    asm volatile("s_waitcnt vmcnt(4)" ::: "memory");
    __builtin_amdgcn_s_barrier();
    __builtin_amdgcn_s_setprio(1);
#pragma unroll
    for (int mf = 0; mf < 4; ++mf)
#pragma unroll
      for (int nf = 0; nf < 2; ++nf)
#pragma unroll
        for (int kk = 0; kk < 2; ++kk)
          acc[mf + 4][nf] = __builtin_amdgcn_mfma_f32_16x16x32_bf16(
              av[mf][kk], bv0[nf][kk], acc[mf + 4][nf], 0, 0, 0);
    __builtin_amdgcn_s_setprio(0);
    __builtin_amdgcn_s_barrier();

    // ---- phase 3: quadrant mf4-7 x nf2-3 ----
    if (st) stA(1, nb, ko);
    asm volatile("s_waitcnt vmcnt(4)" ::: "memory");
    __builtin_amdgcn_s_barrier();
    __builtin_amdgcn_s_setprio(1);
#pragma unroll
    for (int mf = 0; mf < 4; ++mf)
#pragma unroll
      for (int nf = 0; nf < 2; ++nf)
#pragma unroll
        for (int kk = 0; kk < 2; ++kk)
          acc[mf + 4][nf + 2] = __builtin_amdgcn_mfma_f32_16x16x32_bf16(
              av[mf][kk], bv1[nf][kk], acc[mf + 4][nf + 2], 0, 0, 0);
    __builtin_amdgcn_s_setprio(0);
    __builtin_amdgcn_s_barrier();
  }

  // ---- epilogue ----
  const int em = m0 + wm * 128 + (lane >> 4) * 4;
  const int en = n0 + wn * 64 + fr;

  float rdiv[4];
  if (g.epi == 4) {
    const int rbase = (m0 >> 9) << 10;
#pragma unroll
    for (int nf = 0; nf < 4; ++nf)
      rdiv[nf] = 1.f / g.rowsum[rbase + en + nf * 16];
  }

#pragma unroll
  for (int mf = 0; mf < 8; ++mf) {
#pragma unroll
    for (int r = 0; r < 4; ++r) {
      const int gm = em + mf * 16 + r;
      if (g.epi == 2) {  // scores: exp + atomic rowsum of rounded values
        float rsum = 0.f;
#pragma unroll
        for (int nf = 0; nf < 4; ++nf) {
          const int gn = en + nf * 16;
          unsigned short h = f2bf(__expf(acc[mf][nf][r] * g.scale));
          rsum += bf2f(h);
          ((unsigned short*)g.Out)[(size_t)gm * g.ldo + gn] = h;
        }
        rsum += __shfl_xor(rsum, 1);
        rsum += __shfl_xor(rsum, 2);
        rsum += __shfl_xor(rsum, 4);
        rsum += __shfl_xor(rsum, 8);
        if ((lane & 15) == 0) atomicAdd(&g.rowsum[gm], rsum);
        continue;
      }
      if (g.epi == 4) {  // PV': normalize + bias + resid, fp32
        const float bb = g.bias[gm & 511];
#pragma unroll
        for (int nf = 0; nf < 4; ++nf) {
          const int gn = en + nf * 16;
          const size_t off = (size_t)gm * g.ldo + gn;
          ((float*)g.Out)[off] = acc[mf][nf][r] * rdiv[nf] + bb + g.resid[off];
        }
        continue;
      }
#pragma unroll
      for (int nf = 0; nf < 4; ++nf) {  // epi 0 (qk)
        const int gn = en + nf * 16;
        float v = acc[mf][nf][r] * g.scale;
        if (g.bmode == 2) v += g.bias[gn];
        const size_t off = (size_t)gm * g.ldo + gn;
        if (g.obf) ((unsigned short*)g.Out)[off] = f2bf(v);
        else ((float*)g.Out)[off] = v;
      }
    }
  }
}

// ---------------------------------------------------------------------------
extern "C" void kernel_launch(void* const* d_in, const int* in_sizes, int n_in,
                              void* d_out, int out_size, void* d_ws,
                              size_t ws_size, hipStream_t stream) {
  const float* x   = (const float*)d_in[0];
  const float* gsc = (const float*)d_in[1];
  const float* gbi = (const float*)d_in[2];
  const float* wq  = (const float*)d_in[3];
  const float* bq  = (const float*)d_in[4];
  const float* wk  = (const float*)d_in[5];
  const float* bk  = (const float*)d_in[6];
  const float* wv  = (const float*)d_in[7];
  const float* bv  = (const float*)d_in[8];
  const float* wp  = (const float*)d_in[9];
  const float* bp  = (const float*)d_in[10];
  float* out = (float*)d_out;

  char* ws = (char*)d_ws;
  const size_t MB = 1024ull * 1024ull;
  unsigned short* hT  = (unsigned short*)(ws);             // 16MB [16384][512]
  unsigned short* qkT = (unsigned short*)(ws + 16 * MB);   // 32MB [16384][1024]
  unsigned short* E   = (unsigned short*)(ws + 48 * MB);   // 32MB [16384][1024]
  unsigned short* vP  = (unsigned short*)(ws + 80 * MB);   // 16MB [16][512][1024]
  unsigned short* wqk = (unsigned short*)(ws + 96 * MB);   // 1MB  [1024][512]
  unsigned short* W2  = (unsigned short*)(ws + 98 * MB);   // 0.5MB [512][512]
  float*          bqk = (float*)(ws + 99 * MB);            // 4KB
  float*          bpv = (float*)(ws + 99 * MB + 8 * 1024); // 2KB
  float*          rowsum = (float*)(ws + 99 * MB + 16 * 1024);  // 64KB

  prep_kernel<<<1664, 256, 0, stream>>>(x, gsc, gbi, hT, wq, wk, wv, wp,
                                        bq, bk, bv, wqk, W2,
                                        bqk, bpv, rowsum);

  const float rsK = 0.04419417382415922f;  // 512^-0.5

  // qk (gemm8): qkT[m][n] = sum_c hT[m][c] wqk[n][c] + bqk[n]
  GArgs qk{hT, wqk, qkT, bqk, nullptr, nullptr, 0, 0,
           512, 512, 1024, 0, 1, 0, 512, 2, 4, 256, 0, 1.f};
  // scores (gemm8): E[m][j] = exp(rsK * q_m . k_{b,j}); b = m>>10
  GArgs sc{qkT, qkT + 512, E, nullptr, nullptr, rowsum, 1048576, 0,
           1024, 1024, 1024, 10, 1, 0, 512, 0, 4, 256, 2, rsK};
  // vP (old engine): vP[b][co][j] = sum_c W2[co][c] hT[(b,j)][c] + bpv[co]
  GArgs vp{W2, hT, vP, bpv, nullptr, nullptr, 0, 524288,
           512, 512, 1024, 0, 1, 1, 512, 1, 128, 512, 0, 1.f};
  // PV' (gemm8): out[(b,c)][i] = x + bp[c] + (sum_j vP.E)/rowsum; b = m>>9
  GArgs pv{vP, E, out, bp, x, rowsum, 1048576, 0,
           1024, 1024, 1024, 9, 0, 0, 1024, 0, 4, 128, 4, 1.f};

  gemm8<<<256, 512, 0, stream>>>(qk);
  gemm8<<<256, 512, 0, stream>>>(sc);
  gemm_nt<128><<<512, 256, 0, stream>>>(vp, vp, 512);
  gemm8<<<128, 512, 0, stream>>>(pv);
}

// Round 17
// 180.318 us; speedup vs baseline: 1.0642x; 1.0642x over previous
//
#include <hip/hip_runtime.h>
#include <cstdint>
#include <cstddef>

// ---------------------------------------------------------------------------
// AttnBlock, 5 dispatches, every GEMM grid = exactly one resident round:
//   prep:   W2=wp.wv + bpv (0-127); qk-weights float4 (128-383);
//           GN 2-pass, half-live (384-895)
//   qk:     qkT[16384][1024] = hT.wqk^T + bqk        (512 BM256 = 1 round)
//   scores: E[b][i][j] = exp(rsK*q.k); rowsum atomic (512 BM256 = 1 round)
//   vP:     vP[b][co][j] = sum_c W2[co][c] hT[(b,j)][c] + bpv[co] (512 BM128)
//   PV':    out[(b,c)][i] = x + bp[c] + (sum_j vP.E)/rowsum       (512 BM128)
// Engine: BM x 128 tiles, 4 waves, BK=64, chunk-swizzled LDS, XCD remap.
// Pinned lessons: BM256 (256,3) spills (R10: VGPR 84, 344MB scratch);
// grids <= 1 resident round (R12); wave-uniform K-loop global reads
// serialize as s_loads (R13); GN needs explicit float4 2-pass (R14);
// 8-phase schedule loses at K=512 (R16: 8-iter loop never fills pipe).
// ---------------------------------------------------------------------------

typedef __bf16 bf16x8 __attribute__((ext_vector_type(8)));
typedef float f32x4 __attribute__((ext_vector_type(4)));

typedef __attribute__((address_space(1))) const void gl_void;
typedef __attribute__((address_space(3))) void lds_void;

#define GLD16(g, l)                                                     \
  __builtin_amdgcn_global_load_lds((gl_void*)(uintptr_t)(g),            \
                                   (lds_void*)(uintptr_t)(l), 16, 0, 0)

__device__ __forceinline__ unsigned short f2bf(float f) {
  unsigned int u = __builtin_bit_cast(unsigned int, f);
  u += 0x7fffu + ((u >> 16) & 1u);  // round-to-nearest-even
  return (unsigned short)(u >> 16);
}
__device__ __forceinline__ float bf2f(unsigned int h) {
  return __builtin_bit_cast(float, h << 16);
}

// ---- prep: W2 (0-127) + qk weights f4 (128-383) + GN 2-pass (384-895) -----
__global__ __launch_bounds__(256) void prep_kernel(
    const float* __restrict__ x, const float* __restrict__ gsc,
    const float* __restrict__ gbi, unsigned short* __restrict__ hT,
    const float* __restrict__ wq, const float* __restrict__ wk,
    const float* __restrict__ wv, const float* __restrict__ wp,
    const float* __restrict__ bq, const float* __restrict__ bk,
    const float* __restrict__ bv, unsigned short* __restrict__ oqk,
    unsigned short* __restrict__ W2o, float* __restrict__ bqk,
    float* __restrict__ bpv, float* __restrict__ rowsum) {
  const int t = threadIdx.x;
  if (blockIdx.x < 128) {  // ---- W2 = wp.wv (fp32), bpv = wp.bv ----
    __shared__ float swp[4][512];  // wp rows in LDS (broadcast reads)
    __shared__ float sbv[512];
    __shared__ float redp[4][4];
    const int o0 = blockIdx.x * 4;
#pragma unroll
    for (int r = 0; r < 4; ++r) {
      swp[r][t] = wp[(size_t)(o0 + r) * 512 + t];
      swp[r][256 + t] = wp[(size_t)(o0 + r) * 512 + 256 + t];
    }
    sbv[t] = bv[t];
    sbv[256 + t] = bv[256 + t];
    __syncthreads();
    float a0[4] = {}, a1[4] = {};
    for (int c = 0; c < 512; ++c) {
      const float v0 = wv[(size_t)c * 512 + t];        // coalesced
      const float v1 = wv[(size_t)c * 512 + 256 + t];  // coalesced
#pragma unroll
      for (int r = 0; r < 4; ++r) {
        a0[r] = fmaf(swp[r][c], v0, a0[r]);
        a1[r] = fmaf(swp[r][c], v1, a1[r]);
      }
    }
#pragma unroll
    for (int r = 0; r < 4; ++r) {
      W2o[(size_t)(o0 + r) * 512 + t] = f2bf(a0[r]);
      W2o[(size_t)(o0 + r) * 512 + 256 + t] = f2bf(a1[r]);
    }
    float s[4];
#pragma unroll
    for (int r = 0; r < 4; ++r)
      s[r] = swp[r][t] * sbv[t] + swp[r][256 + t] * sbv[256 + t];
#pragma unroll
    for (int r = 0; r < 4; ++r)
#pragma unroll
      for (int off = 32; off > 0; off >>= 1) s[r] += __shfl_down(s[r], off);
    if ((t & 63) == 0) {
#pragma unroll
      for (int r = 0; r < 4; ++r) redp[r][t >> 6] = s[r];
    }
    __syncthreads();
    if (t == 0) {
#pragma unroll
      for (int r = 0; r < 4; ++r)
        bpv[o0 + r] = redp[r][0] + redp[r][1] + redp[r][2] + redp[r][3];
    }
    return;
  }
  if (blockIdx.x < 384) {  // ---- qk weights float4 -> bf16, bias, rowsum ----
    const int q4 = (blockIdx.x - 128) * 256 + t;  // float4 index 0..65535
    const float4 a = ((const float4*)wq)[q4];
    const float4 b = ((const float4*)wk)[q4];
    uint2 pa, pb;
    pa.x = (unsigned int)f2bf(a.x) | ((unsigned int)f2bf(a.y) << 16);
    pa.y = (unsigned int)f2bf(a.z) | ((unsigned int)f2bf(a.w) << 16);
    pb.x = (unsigned int)f2bf(b.x) | ((unsigned int)f2bf(b.y) << 16);
    pb.y = (unsigned int)f2bf(b.z) | ((unsigned int)f2bf(b.w) << 16);
    ((uint2*)oqk)[q4] = pa;
    ((uint2*)oqk)[65536 + q4] = pb;
    if (q4 < 128) ((float4*)bqk)[q4] = ((const float4*)bq)[q4];
    else if (q4 < 256) ((float4*)bqk)[q4] = ((const float4*)bk)[q4 - 128];
    if (q4 < 4096)
      ((float4*)rowsum)[q4] = make_float4(0.f, 0.f, 0.f, 0.f);
    return;
  }
  // ---- GroupNorm -> hT[b][i][c] bf16; pass1 keeps chans 0-7 live ----
  __shared__ float red[2][4];
  const int gb = blockIdx.x - 384;
  const int b = gb >> 5;
  const int g = gb & 31;
  const int wid = t >> 6, lane = t & 63;
  const float* xp = x + ((size_t)(b * 512 + g * 16)) * 1024;

  float4 r4[8];  // channels 0-7 stay live through the reduction (32 VGPR)
  float s = 0.f, s2 = 0.f;
#pragma unroll
  for (int c = 0; c < 8; ++c) {
    r4[c] = ((const float4*)(xp + (size_t)c * 1024))[t];
    s += (r4[c].x + r4[c].y) + (r4[c].z + r4[c].w);
    s2 += (r4[c].x * r4[c].x + r4[c].y * r4[c].y) +
          (r4[c].z * r4[c].z + r4[c].w * r4[c].w);
  }
#pragma unroll
  for (int c = 8; c < 16; ++c) {
    const float4 v = ((const float4*)(xp + (size_t)c * 1024))[t];
    s += (v.x + v.y) + (v.z + v.w);
    s2 += (v.x * v.x + v.y * v.y) + (v.z * v.z + v.w * v.w);
  }
#pragma unroll
  for (int off = 32; off > 0; off >>= 1) {
    s += __shfl_down(s, off);
    s2 += __shfl_down(s2, off);
  }
  if (lane == 0) { red[0][wid] = s; red[1][wid] = s2; }
  __syncthreads();
  const float S = red[0][0] + red[0][1] + red[0][2] + red[0][3];
  const float S2 = red[1][0] + red[1][1] + red[1][2] + red[1][3];
  const float mean = S * (1.f / 16384.f);
  const float var = S2 * (1.f / 16384.f) - mean * mean;
  const float rstd = rsqrtf(var + 1e-6f);

  float sc[16], bi[16];
#pragma unroll
  for (int c = 0; c < 16; ++c) {
    sc[c] = gsc[g * 16 + c] * rstd;
    bi[c] = gbi[g * 16 + c] - mean * sc[c];
  }
  unsigned short* hp = hT + (size_t)b * 1024 * 512 + g * 16;
#pragma unroll
  for (int half = 0; half < 2; ++half) {
    if (half == 1) {  // re-read channels 8-15 (L2-hot) into the same regs
#pragma unroll
      for (int c = 0; c < 8; ++c)
        r4[c] = ((const float4*)(xp + (size_t)(8 + c) * 1024))[t];
    }
#pragma unroll
    for (int ii = 0; ii < 4; ++ii) {  // float4 component = row 4t+ii
      const int i = 4 * t + ii;
      unsigned int pk[4];
#pragma unroll
      for (int p = 0; p < 4; ++p) {
        const int c0 = half * 8 + 2 * p;
        float e0, e1;
        if (ii == 0) { e0 = r4[2 * p].x; e1 = r4[2 * p + 1].x; }
        else if (ii == 1) { e0 = r4[2 * p].y; e1 = r4[2 * p + 1].y; }
        else if (ii == 2) { e0 = r4[2 * p].z; e1 = r4[2 * p + 1].z; }
        else { e0 = r4[2 * p].w; e1 = r4[2 * p + 1].w; }
        const float v0 = e0 * sc[c0] + bi[c0];
        const float v1 = e1 * sc[c0 + 1] + bi[c0 + 1];
        pk[p] = (unsigned int)f2bf(v0) | ((unsigned int)f2bf(v1) << 16);
      }
      *(uint4*)(hp + (size_t)i * 512 + half * 8) =
          make_uint4(pk[0], pk[1], pk[2], pk[3]);
    }
  }
}

// ------------------------- NT GEMM engine ----------------------------------
// D[m][n] = scale * sum_k A[m][k]*Bt[n][k].
// epi 0: plain  (+bias bmode{1:[gm],2:[gn]}, +resid, csplit offset)
// epi 2: exp + atomic rowsum (scores; bf16 out, row-major)
// epi 4: PV': v/rowsum[(m0>>9)*1024+gn] + bias[gm&511] + resid; fp32 row-major
struct GArgs {
  const unsigned short *A, *B;
  void* Out;
  const float *bias, *resid;
  float* rowsum;
  long long sBb, sOb;
  int lda, ldb, ldo, btshift, obf, csplit, K, bmode, nx, nwg, epi;
  float scale;
};

template <int BM>
__global__ __launch_bounds__(256, (BM == 256 ? 2 : 3)) void gemm_nt(
    GArgs g0, GArgs g1, int split) {
  constexpr int MF = BM / 32;      // m-frags per wave (8 / 4)
  constexpr int WMS = BM / 2;      // wave m-span (128 / 64)
  constexpr int ASLABS = BM / 32;  // A staging slabs (8 / 4)
  constexpr int BOFF = BM * 128;   // byte offset of B region in LDS
  __shared__ char lds[BM * 128 + 16384];

  const bool r1 = (int)blockIdx.x >= split;
  const GArgs g = r1 ? g1 : g0;
  const int lid = blockIdx.x - (r1 ? split : 0);

  // XCD-chunked remap within role (nwg % 8 == 0 for all our grids)
  const int cpx = g.nwg >> 3;
  const int rid = (lid & 7) * cpx + (lid >> 3);
  const int bx = rid % g.nx, by = rid / g.nx;
  const int m0 = by * BM, n0 = bx * 128;

  const int t = threadIdx.x;
  const int wid = t >> 6, lane = t & 63;
  const int srow = t >> 3;                        // 32-row slab row
  const int schunk = ((t & 7) ^ (srow & 7)) * 8;  // pre-swizzled src chunk
  const unsigned short* gA = g.A + (size_t)(m0 + srow) * g.lda + schunk;
  const unsigned short* gB =
      g.B + (g.btshift ? (size_t)(m0 >> g.btshift) * g.sBb : 0) +
      (size_t)(n0 + srow) * g.ldb + schunk;
  const int stgO = wid << 10;  // wave-uniform 1KB sub-slab

  f32x4 acc[MF][4] = {};
  const int wm = wid >> 1, wn = wid & 1;
  const int fr = lane & 15;
  const int slot0 = (((lane >> 4) ^ (fr & 7)) << 4);
  const int aoff = (wm * WMS + fr) * 128 + slot0;
  const int boff = BOFF + (wn * 64 + fr) * 128 + slot0;

  const int nt = g.K >> 6;
  for (int tt = 0; tt < nt; ++tt) {
    const size_t ko = (size_t)tt * 64;
#pragma unroll
    for (int c = 0; c < ASLABS; ++c)
      GLD16(gA + ko + (size_t)(c * 32) * g.lda, lds + c * 4096 + stgO);
#pragma unroll
    for (int c = 0; c < 4; ++c)
      GLD16(gB + ko + (size_t)(c * 32) * g.ldb, lds + BOFF + c * 4096 + stgO);
    __syncthreads();  // drains vmcnt -> tile visible to all waves
#pragma unroll
    for (int kk = 0; kk < 2; ++kk) {
      const int kx = kk ? 64 : 0;  // second k-half: chunk slot ^= 4
      bf16x8 av[MF], bv[4];
#pragma unroll
      for (int mf = 0; mf < MF; ++mf)
        av[mf] = *(const bf16x8*)(lds + ((aoff + mf * 2048) ^ kx));
#pragma unroll
      for (int nf = 0; nf < 4; ++nf)
        bv[nf] = *(const bf16x8*)(lds + ((boff + nf * 2048) ^ kx));
      __builtin_amdgcn_s_setprio(1);
#pragma unroll
      for (int mf = 0; mf < MF; ++mf)
#pragma unroll
        for (int nf = 0; nf < 4; ++nf)
          acc[mf][nf] = __builtin_amdgcn_mfma_f32_16x16x32_bf16(
              av[mf], bv[nf], acc[mf][nf], 0, 0, 0);
      __builtin_amdgcn_s_setprio(0);
    }
    __syncthreads();  // protect LDS before next stage
  }

  const int em = m0 + wm * WMS + (lane >> 4) * 4;
  const int en = n0 + wn * 64 + fr;

  float rdiv[4];
  if (g.epi == 4) {
    const int rbase = (m0 >> 9) << 10;  // batch = m0>>9, E-row base
#pragma unroll
    for (int nf = 0; nf < 4; ++nf)
      rdiv[nf] = 1.f / g.rowsum[rbase + en + nf * 16];
  }

#pragma unroll
  for (int mf = 0; mf < MF; ++mf) {
#pragma unroll
    for (int r = 0; r < 4; ++r) {
      const int gm = em + mf * 16 + r;
      if (g.epi == 2) {  // scores: exp, atomic row sum of ROUNDED values
        float rsum = 0.f;
#pragma unroll
        for (int nf = 0; nf < 4; ++nf) {
          const int gn = en + nf * 16;
          unsigned short h = f2bf(__expf(acc[mf][nf][r] * g.scale));
          rsum += bf2f(h);
          ((unsigned short*)g.Out)[(size_t)gm * g.ldo + gn] = h;
        }
        rsum += __shfl_xor(rsum, 1);
        rsum += __shfl_xor(rsum, 2);
        rsum += __shfl_xor(rsum, 4);
        rsum += __shfl_xor(rsum, 8);
        if ((lane & 15) == 0) atomicAdd(&g.rowsum[gm], rsum);
        continue;
      }
      if (g.epi == 4) {  // PV': normalize + bias + resid, fp32 row-major
        const float bb = g.bias[gm & 511];
#pragma unroll
        for (int nf = 0; nf < 4; ++nf) {
          const int gn = en + nf * 16;
          const size_t off = (size_t)gm * g.ldo + gn;
          ((float*)g.Out)[off] = acc[mf][nf][r] * rdiv[nf] + bb + g.resid[off];
        }
        continue;
      }
#pragma unroll
      for (int nf = 0; nf < 4; ++nf) {
        const int gn = en + nf * 16;
        float v = acc[mf][nf][r] * g.scale;
        if (g.bmode == 1) v += g.bias[gm];
        else if (g.bmode == 2) v += g.bias[gn];
        size_t off;
        if (g.csplit)
          off = (size_t)(gn >> 10) * g.sOb + (size_t)gm * g.ldo + (gn & 1023);
        else
          off = (size_t)gm * g.ldo + gn;
        if (g.resid) v += g.resid[off];
        if (g.obf) ((unsigned short*)g.Out)[off] = f2bf(v);
        else ((float*)g.Out)[off] = v;
      }
    }
  }
}

// ---------------------------------------------------------------------------
extern "C" void kernel_launch(void* const* d_in, const int* in_sizes, int n_in,
                              void* d_out, int out_size, void* d_ws,
                              size_t ws_size, hipStream_t stream) {
  const float* x   = (const float*)d_in[0];
  const float* gsc = (const float*)d_in[1];
  const float* gbi = (const float*)d_in[2];
  const float* wq  = (const float*)d_in[3];
  const float* bq  = (const float*)d_in[4];
  const float* wk  = (const float*)d_in[5];
  const float* bk  = (const float*)d_in[6];
  const float* wv  = (const float*)d_in[7];
  const float* bv  = (const float*)d_in[8];
  const float* wp  = (const float*)d_in[9];
  const float* bp  = (const float*)d_in[10];
  float* out = (float*)d_out;

  char* ws = (char*)d_ws;
  const size_t MB = 1024ull * 1024ull;
  unsigned short* hT  = (unsigned short*)(ws);             // 16MB [16384][512]
  unsigned short* qkT = (unsigned short*)(ws + 16 * MB);   // 32MB [16384][1024]
  unsigned short* E   = (unsigned short*)(ws + 48 * MB);   // 32MB [16384][1024]
  unsigned short* vP  = (unsigned short*)(ws + 80 * MB);   // 16MB [16][512][1024]
  unsigned short* wqk = (unsigned short*)(ws + 96 * MB);   // 1MB  [1024][512]
  unsigned short* W2  = (unsigned short*)(ws + 98 * MB);   // 0.5MB [512][512]
  float*          bqk = (float*)(ws + 99 * MB);            // 4KB
  float*          bpv = (float*)(ws + 99 * MB + 8 * 1024); // 2KB
  float*          rowsum = (float*)(ws + 99 * MB + 16 * 1024);  // 64KB

  prep_kernel<<<896, 256, 0, stream>>>(x, gsc, gbi, hT, wq, wk, wv, wp,
                                       bq, bk, bv, wqk, W2,
                                       bqk, bpv, rowsum);

  const float rsK = 0.04419417382415922f;  // 512^-0.5

  // qk: qkT[m][n] = sum_c hT[m][c] wqk[n][c] + bqk[n]  (512 tiles, 1 round)
  GArgs qk{hT, wqk, qkT, bqk, nullptr, nullptr, 0, 0,
           512, 512, 1024, 0, 1, 0, 512, 2, 8, 512, 0, 1.f};
  // scores: E[m][j] = exp(rsK * q_m . k_{b,j}); rowsum atomic. b = m>>10.
  GArgs sc{qkT, qkT + 512, E, nullptr, nullptr, rowsum, 1048576, 0,
           1024, 1024, 1024, 10, 1, 0, 512, 0, 8, 512, 2, rsK};
  // vP[b][co][j] = sum_c W2[co][c] hT[(b,j)][c] + bpv[co]  (csplit writes)
  GArgs vp{W2, hT, vP, bpv, nullptr, nullptr, 0, 524288,
           512, 512, 1024, 0, 1, 1, 512, 1, 128, 512, 0, 1.f};
  // PV': out[(b,c)][i] = x + bp[c] + (sum_j vP[(b,c)][j] E[b][i][j])/rowsum
  GArgs pv{vP, E, out, bp, x, rowsum, 1048576, 0,
           1024, 1024, 1024, 9, 0, 0, 1024, 0, 8, 512, 4, 1.f};

  gemm_nt<256><<<512, 256, 0, stream>>>(qk, qk, 512);
  gemm_nt<256><<<512, 256, 0, stream>>>(sc, sc, 512);
  gemm_nt<128><<<512, 256, 0, stream>>>(vp, vp, 512);
  gemm_nt<128><<<512, 256, 0, stream>>>(pv, pv, 512);
}

// Round 18
// 157.203 us; speedup vs baseline: 1.2206x; 1.1470x over previous
//
#include <hip/hip_runtime.h>
#include <cstdint>
#include <cstddef>

// ---------------------------------------------------------------------------
// AttnBlock, 4 dispatches, every GEMM grid = exactly one resident round:
//   prep:   W2=wp.wv + bpv + rowsum=0 (0-127); WqkT=rsK*wk^T.wq + cu (128-255);
//           GN 2-pass half-live -> hT[16384][512] (256-767)
//   tmp|vP: tmp[16384][512] = hT.WqkT^T + cu   (256 BM256 tiles)
//           vP[b][co][j] = W2.hT + bpv          (256 BM256 tiles, csplit)
//   scores: E[b][i][j] = exp(tmp_i . hT_j); rowsum atomic (512 BM256)
//   PV':    out[(b,c)][i] = x + bp[c] + (sum_j vP.E)/rowsum (512 BM128)
// Key algebra: S = q.k = hT.(wq^T wk).hT + (wk^T bq).hT_j + [i-only + const]
// -- i-only and const terms cancel in softmax over j (shift invariance), so
// qk (17.2GF, full round) is replaced by tmp (8.6GF) which PAIRS with vP in
// one round. rsK folded into WqkT/cu.
// Pinned lessons: BM256 (256,3) spills (R10); grids = 1 resident round (R12);
// wave-uniform K-loop global reads serialize as s_loads -> LDS-stage (R13);
// GN explicit float4 2-pass (R14); 8-phase loses at K=512 (R16).
// ---------------------------------------------------------------------------

typedef __bf16 bf16x8 __attribute__((ext_vector_type(8)));
typedef float f32x4 __attribute__((ext_vector_type(4)));

typedef __attribute__((address_space(1))) const void gl_void;
typedef __attribute__((address_space(3))) void lds_void;

#define GLD16(g, l)                                                     \
  __builtin_amdgcn_global_load_lds((gl_void*)(uintptr_t)(g),            \
                                   (lds_void*)(uintptr_t)(l), 16, 0, 0)

__device__ __forceinline__ unsigned short f2bf(float f) {
  unsigned int u = __builtin_bit_cast(unsigned int, f);
  u += 0x7fffu + ((u >> 16) & 1u);  // round-to-nearest-even
  return (unsigned short)(u >> 16);
}
__device__ __forceinline__ float bf2f(unsigned int h) {
  return __builtin_bit_cast(float, h << 16);
}

// ---- prep: W2 (0-127) + WqkT/cu (128-255) + GN 2-pass (256-767) -----------
__global__ __launch_bounds__(256) void prep_kernel(
    const float* __restrict__ x, const float* __restrict__ gsc,
    const float* __restrict__ gbi, unsigned short* __restrict__ hT,
    const float* __restrict__ wq, const float* __restrict__ wk,
    const float* __restrict__ wv, const float* __restrict__ wp,
    const float* __restrict__ bq, const float* __restrict__ bv,
    unsigned short* __restrict__ WqkTo, unsigned short* __restrict__ W2o,
    float* __restrict__ cu, float* __restrict__ bpv,
    float* __restrict__ rowsum, float rsK) {
  const int t = threadIdx.x;
  if (blockIdx.x < 128) {  // ---- W2 = wp.wv (fp32), bpv = wp.bv, rowsum=0 ----
    __shared__ float swp[4][512];  // wp rows in LDS (broadcast reads)
    __shared__ float sbv[512];
    __shared__ float redp[4][4];
    const int o0 = blockIdx.x * 4;
#pragma unroll
    for (int r = 0; r < 4; ++r) {
      swp[r][t] = wp[(size_t)(o0 + r) * 512 + t];
      swp[r][256 + t] = wp[(size_t)(o0 + r) * 512 + 256 + t];
    }
    sbv[t] = bv[t];
    sbv[256 + t] = bv[256 + t];
    if (t < 128) rowsum[blockIdx.x * 128 + t] = 0.f;  // 128*128 = 16384
    __syncthreads();
    float a0[4] = {}, a1[4] = {};
    for (int c = 0; c < 512; ++c) {
      const float v0 = wv[(size_t)c * 512 + t];        // coalesced
      const float v1 = wv[(size_t)c * 512 + 256 + t];  // coalesced
#pragma unroll
      for (int r = 0; r < 4; ++r) {
        a0[r] = fmaf(swp[r][c], v0, a0[r]);
        a1[r] = fmaf(swp[r][c], v1, a1[r]);
      }
    }
#pragma unroll
    for (int r = 0; r < 4; ++r) {
      W2o[(size_t)(o0 + r) * 512 + t] = f2bf(a0[r]);
      W2o[(size_t)(o0 + r) * 512 + 256 + t] = f2bf(a1[r]);
    }
    float s[4];
#pragma unroll
    for (int r = 0; r < 4; ++r)
      s[r] = swp[r][t] * sbv[t] + swp[r][256 + t] * sbv[256 + t];
#pragma unroll
    for (int r = 0; r < 4; ++r)
#pragma unroll
      for (int off = 32; off > 0; off >>= 1) s[r] += __shfl_down(s[r], off);
    if ((t & 63) == 0) {
#pragma unroll
      for (int r = 0; r < 4; ++r) redp[r][t >> 6] = s[r];
    }
    __syncthreads();
    if (t == 0) {
#pragma unroll
      for (int r = 0; r < 4; ++r)
        bpv[o0 + r] = redp[r][0] + redp[r][1] + redp[r][2] + redp[r][3];
    }
    return;
  }
  if (blockIdx.x < 256) {  // ---- WqkT[n][c] = rsK*sum_o wk[o][n] wq[o][c] ----
    __shared__ float swk[512][4];  // wk cols n0..n0+3 (staged via float4 rows)
    __shared__ float sbq[512];
    __shared__ float redq[4][4];
    const int n0 = (blockIdx.x - 128) * 4;
    *(float4*)&swk[t][0] = *(const float4*)&wk[(size_t)t * 512 + n0];
    *(float4*)&swk[256 + t][0] =
        *(const float4*)&wk[(size_t)(256 + t) * 512 + n0];
    sbq[t] = bq[t];
    sbq[256 + t] = bq[256 + t];
    __syncthreads();
    float a0[4] = {}, a1[4] = {};
    for (int o = 0; o < 512; ++o) {
      const float q0 = wq[(size_t)o * 512 + t];        // coalesced
      const float q1 = wq[(size_t)o * 512 + 256 + t];  // coalesced
#pragma unroll
      for (int r = 0; r < 4; ++r) {  // swk[o][r]: LDS broadcast
        a0[r] = fmaf(swk[o][r], q0, a0[r]);
        a1[r] = fmaf(swk[o][r], q1, a1[r]);
      }
    }
#pragma unroll
    for (int r = 0; r < 4; ++r) {
      WqkTo[(size_t)(n0 + r) * 512 + t] = f2bf(a0[r] * rsK);
      WqkTo[(size_t)(n0 + r) * 512 + 256 + t] = f2bf(a1[r] * rsK);
    }
    // cu[n0+r] = rsK * sum_o wk[o][n0+r]*bq[o]
    float s[4];
#pragma unroll
    for (int r = 0; r < 4; ++r)
      s[r] = swk[t][r] * sbq[t] + swk[256 + t][r] * sbq[256 + t];
#pragma unroll
    for (int r = 0; r < 4; ++r)
#pragma unroll
      for (int off = 32; off > 0; off >>= 1) s[r] += __shfl_down(s[r], off);
    if ((t & 63) == 0) {
#pragma unroll
      for (int r = 0; r < 4; ++r) redq[r][t >> 6] = s[r];
    }
    __syncthreads();
    if (t == 0) {
#pragma unroll
      for (int r = 0; r < 4; ++r)
        cu[n0 + r] =
            rsK * (redq[r][0] + redq[r][1] + redq[r][2] + redq[r][3]);
    }
    return;
  }
  // ---- GroupNorm -> hT[b][i][c] bf16; pass1 keeps chans 0-7 live ----
  __shared__ float red[2][4];
  const int gb = blockIdx.x - 256;
  const int b = gb >> 5;
  const int g = gb & 31;
  const int wid = t >> 6, lane = t & 63;
  const float* xp = x + ((size_t)(b * 512 + g * 16)) * 1024;

  float4 r4[8];  // channels 0-7 live through the reduction (32 VGPR)
  float s = 0.f, s2 = 0.f;
#pragma unroll
  for (int c = 0; c < 8; ++c) {
    r4[c] = ((const float4*)(xp + (size_t)c * 1024))[t];
    s += (r4[c].x + r4[c].y) + (r4[c].z + r4[c].w);
    s2 += (r4[c].x * r4[c].x + r4[c].y * r4[c].y) +
          (r4[c].z * r4[c].z + r4[c].w * r4[c].w);
  }
#pragma unroll
  for (int c = 8; c < 16; ++c) {
    const float4 v = ((const float4*)(xp + (size_t)c * 1024))[t];
    s += (v.x + v.y) + (v.z + v.w);
    s2 += (v.x * v.x + v.y * v.y) + (v.z * v.z + v.w * v.w);
  }
#pragma unroll
  for (int off = 32; off > 0; off >>= 1) {
    s += __shfl_down(s, off);
    s2 += __shfl_down(s2, off);
  }
  if (lane == 0) { red[0][wid] = s; red[1][wid] = s2; }
  __syncthreads();
  const float S = red[0][0] + red[0][1] + red[0][2] + red[0][3];
  const float S2 = red[1][0] + red[1][1] + red[1][2] + red[1][3];
  const float mean = S * (1.f / 16384.f);
  const float var = S2 * (1.f / 16384.f) - mean * mean;
  const float rstd = rsqrtf(var + 1e-6f);

  float sc[16], bi[16];
#pragma unroll
  for (int c = 0; c < 16; ++c) {
    sc[c] = gsc[g * 16 + c] * rstd;
    bi[c] = gbi[g * 16 + c] - mean * sc[c];
  }
  unsigned short* hp = hT + (size_t)b * 1024 * 512 + g * 16;
#pragma unroll
  for (int half = 0; half < 2; ++half) {
    if (half == 1) {  // re-read channels 8-15 (L2-hot)
#pragma unroll
      for (int c = 0; c < 8; ++c)
        r4[c] = ((const float4*)(xp + (size_t)(8 + c) * 1024))[t];
    }
#pragma unroll
    for (int ii = 0; ii < 4; ++ii) {  // float4 component = row 4t+ii
      const int i = 4 * t + ii;
      unsigned int pk[4];
#pragma unroll
      for (int p = 0; p < 4; ++p) {
        const int c0 = half * 8 + 2 * p;
        float e0, e1;
        if (ii == 0) { e0 = r4[2 * p].x; e1 = r4[2 * p + 1].x; }
        else if (ii == 1) { e0 = r4[2 * p].y; e1 = r4[2 * p + 1].y; }
        else if (ii == 2) { e0 = r4[2 * p].z; e1 = r4[2 * p + 1].z; }
        else { e0 = r4[2 * p].w; e1 = r4[2 * p + 1].w; }
        const float v0 = e0 * sc[c0] + bi[c0];
        const float v1 = e1 * sc[c0 + 1] + bi[c0 + 1];
        pk[p] = (unsigned int)f2bf(v0) | ((unsigned int)f2bf(v1) << 16);
      }
      *(uint4*)(hp + (size_t)i * 512 + half * 8) =
          make_uint4(pk[0], pk[1], pk[2], pk[3]);
    }
  }
}

// ------------------------- NT GEMM engine ----------------------------------
// D[m][n] = scale * sum_k A[m][k]*Bt[n][k].
// epi 0: plain  (+bias bmode{1:[gm],2:[gn]}, +resid, csplit offset)
// epi 2: exp + atomic rowsum (scores; bf16 out, row-major)
// epi 4: PV': v/rowsum[(m0>>9)*1024+gn] + bias[gm&511] + resid; fp32 row-major
struct GArgs {
  const unsigned short *A, *B;
  void* Out;
  const float *bias, *resid;
  float* rowsum;
  long long sBb, sOb;
  int lda, ldb, ldo, btshift, obf, csplit, K, bmode, nx, nwg, epi;
  float scale;
};

template <int BM>
__global__ __launch_bounds__(256, (BM == 256 ? 2 : 3)) void gemm_nt(
    GArgs g0, GArgs g1, int split) {
  constexpr int MF = BM / 32;      // m-frags per wave (8 / 4)
  constexpr int WMS = BM / 2;      // wave m-span (128 / 64)
  constexpr int ASLABS = BM / 32;  // A staging slabs (8 / 4)
  constexpr int BOFF = BM * 128;   // byte offset of B region in LDS
  __shared__ char lds[BM * 128 + 16384];

  const bool r1 = (int)blockIdx.x >= split;
  const GArgs g = r1 ? g1 : g0;
  const int lid = blockIdx.x - (r1 ? split : 0);

  // XCD-chunked remap within role (nwg % 8 == 0 for all our grids)
  const int cpx = g.nwg >> 3;
  const int rid = (lid & 7) * cpx + (lid >> 3);
  const int bx = rid % g.nx, by = rid / g.nx;
  const int m0 = by * BM, n0 = bx * 128;

  const int t = threadIdx.x;
  const int wid = t >> 6, lane = t & 63;
  const int srow = t >> 3;                        // 32-row slab row
  const int schunk = ((t & 7) ^ (srow & 7)) * 8;  // pre-swizzled src chunk
  const unsigned short* gA = g.A + (size_t)(m0 + srow) * g.lda + schunk;
  const unsigned short* gB =
      g.B + (g.btshift ? (size_t)(m0 >> g.btshift) * g.sBb : 0) +
      (size_t)(n0 + srow) * g.ldb + schunk;
  const int stgO = wid << 10;  // wave-uniform 1KB sub-slab

  f32x4 acc[MF][4] = {};
  const int wm = wid >> 1, wn = wid & 1;
  const int fr = lane & 15;
  const int slot0 = (((lane >> 4) ^ (fr & 7)) << 4);
  const int aoff = (wm * WMS + fr) * 128 + slot0;
  const int boff = BOFF + (wn * 64 + fr) * 128 + slot0;

  const int nt = g.K >> 6;
  for (int tt = 0; tt < nt; ++tt) {
    const size_t ko = (size_t)tt * 64;
#pragma unroll
    for (int c = 0; c < ASLABS; ++c)
      GLD16(gA + ko + (size_t)(c * 32) * g.lda, lds + c * 4096 + stgO);
#pragma unroll
    for (int c = 0; c < 4; ++c)
      GLD16(gB + ko + (size_t)(c * 32) * g.ldb, lds + BOFF + c * 4096 + stgO);
    __syncthreads();  // drains vmcnt -> tile visible to all waves
#pragma unroll
    for (int kk = 0; kk < 2; ++kk) {
      const int kx = kk ? 64 : 0;  // second k-half: chunk slot ^= 4
      bf16x8 av[MF], bv[4];
#pragma unroll
      for (int mf = 0; mf < MF; ++mf)
        av[mf] = *(const bf16x8*)(lds + ((aoff + mf * 2048) ^ kx));
#pragma unroll
      for (int nf = 0; nf < 4; ++nf)
        bv[nf] = *(const bf16x8*)(lds + ((boff + nf * 2048) ^ kx));
      __builtin_amdgcn_s_setprio(1);
#pragma unroll
      for (int mf = 0; mf < MF; ++mf)
#pragma unroll
        for (int nf = 0; nf < 4; ++nf)
          acc[mf][nf] = __builtin_amdgcn_mfma_f32_16x16x32_bf16(
              av[mf], bv[nf], acc[mf][nf], 0, 0, 0);
      __builtin_amdgcn_s_setprio(0);
    }
    __syncthreads();  // protect LDS before next stage
  }

  const int em = m0 + wm * WMS + (lane >> 4) * 4;
  const int en = n0 + wn * 64 + fr;

  float rdiv[4];
  if (g.epi == 4) {
    const int rbase = (m0 >> 9) << 10;  // batch = m0>>9, E-row base
#pragma unroll
    for (int nf = 0; nf < 4; ++nf)
      rdiv[nf] = 1.f / g.rowsum[rbase + en + nf * 16];
  }

#pragma unroll
  for (int mf = 0; mf < MF; ++mf) {
#pragma unroll
    for (int r = 0; r < 4; ++r) {
      const int gm = em + mf * 16 + r;
      if (g.epi == 2) {  // scores: exp, atomic row sum of ROUNDED values
        float rsum = 0.f;
#pragma unroll
        for (int nf = 0; nf < 4; ++nf) {
          const int gn = en + nf * 16;
          unsigned short h = f2bf(__expf(acc[mf][nf][r] * g.scale));
          rsum += bf2f(h);
          ((unsigned short*)g.Out)[(size_t)gm * g.ldo + gn] = h;
        }
        rsum += __shfl_xor(rsum, 1);
        rsum += __shfl_xor(rsum, 2);
        rsum += __shfl_xor(rsum, 4);
        rsum += __shfl_xor(rsum, 8);
        if ((lane & 15) == 0) atomicAdd(&g.rowsum[gm], rsum);
        continue;
      }
      if (g.epi == 4) {  // PV': normalize + bias + resid, fp32 row-major
        const float bb = g.bias[gm & 511];
#pragma unroll
        for (int nf = 0; nf < 4; ++nf) {
          const int gn = en + nf * 16;
          const size_t off = (size_t)gm * g.ldo + gn;
          ((float*)g.Out)[off] = acc[mf][nf][r] * rdiv[nf] + bb + g.resid[off];
        }
        continue;
      }
#pragma unroll
      for (int nf = 0; nf < 4; ++nf) {
        const int gn = en + nf * 16;
        float v = acc[mf][nf][r] * g.scale;
        if (g.bmode == 1) v += g.bias[gm];
        else if (g.bmode == 2) v += g.bias[gn];
        size_t off;
        if (g.csplit)
          off = (size_t)(gn >> 10) * g.sOb + (size_t)gm * g.ldo + (gn & 1023);
        else
          off = (size_t)gm * g.ldo + gn;
        if (g.resid) v += g.resid[off];
        if (g.obf) ((unsigned short*)g.Out)[off] = f2bf(v);
        else ((float*)g.Out)[off] = v;
      }
    }
  }
}

// ---------------------------------------------------------------------------
extern "C" void kernel_launch(void* const* d_in, const int* in_sizes, int n_in,
                              void* d_out, int out_size, void* d_ws,
                              size_t ws_size, hipStream_t stream) {
  const float* x   = (const float*)d_in[0];
  const float* gsc = (const float*)d_in[1];
  const float* gbi = (const float*)d_in[2];
  const float* wq  = (const float*)d_in[3];
  const float* bq  = (const float*)d_in[4];
  const float* wk  = (const float*)d_in[5];
  const float* wv  = (const float*)d_in[7];
  const float* bv  = (const float*)d_in[8];
  const float* wp  = (const float*)d_in[9];
  const float* bp  = (const float*)d_in[10];
  float* out = (float*)d_out;

  char* ws = (char*)d_ws;
  const size_t MB = 1024ull * 1024ull;
  unsigned short* hT   = (unsigned short*)(ws);             // 16MB [16384][512]
  unsigned short* tmpB = (unsigned short*)(ws + 16 * MB);   // 16MB [16384][512]
  unsigned short* E    = (unsigned short*)(ws + 48 * MB);   // 32MB [16384][1024]
  unsigned short* vP   = (unsigned short*)(ws + 80 * MB);   // 16MB [16][512][1024]
  unsigned short* WqkT = (unsigned short*)(ws + 96 * MB);   // 0.5MB [512][512]
  unsigned short* W2   = (unsigned short*)(ws + 98 * MB);   // 0.5MB [512][512]
  float*          cu   = (float*)(ws + 99 * MB);            // 2KB
  float*          bpv  = (float*)(ws + 99 * MB + 8 * 1024); // 2KB
  float*          rowsum = (float*)(ws + 99 * MB + 16 * 1024);  // 64KB

  const float rsK = 0.04419417382415922f;  // 512^-0.5

  prep_kernel<<<768, 256, 0, stream>>>(x, gsc, gbi, hT, wq, wk, wv, wp,
                                       bq, bv, WqkT, W2, cu, bpv, rowsum,
                                       rsK);

  // tmp[m][n] = sum_c hT[m][c] WqkT[n][c] + cu[n]   (rsK pre-folded)
  GArgs tg{hT, WqkT, tmpB, cu, nullptr, nullptr, 0, 0,
           512, 512, 512, 0, 1, 0, 512, 2, 4, 256, 0, 1.f};
  // vP[b][co][j] = sum_c W2[co][c] hT[(b,j)][c] + bpv[co]  (csplit writes)
  GArgs vp{W2, hT, vP, bpv, nullptr, nullptr, 0, 524288,
           512, 512, 1024, 0, 1, 1, 512, 1, 128, 256, 0, 1.f};
  // scores: E[m][j] = exp(tmp_m . hT_{b,j}); rowsum atomic. b = m>>10.
  GArgs sc{tmpB, hT, E, nullptr, nullptr, rowsum, 524288, 0,
           512, 512, 1024, 10, 1, 0, 512, 0, 8, 512, 2, 1.f};
  // PV': out[(b,c)][i] = x + bp[c] + (sum_j vP[(b,c)][j] E[b][i][j])/rowsum
  GArgs pv{vP, E, out, bp, x, rowsum, 1048576, 0,
           1024, 1024, 1024, 9, 0, 0, 1024, 0, 8, 512, 4, 1.f};

  gemm_nt<256><<<512, 256, 0, stream>>>(tg, vp, 256);  // tmp || vP, 1 round
  gemm_nt<256><<<512, 256, 0, stream>>>(sc, sc, 512);
  gemm_nt<128><<<512, 256, 0, stream>>>(pv, pv, 512);
}

// Round 19
// 155.966 us; speedup vs baseline: 1.2303x; 1.0079x over previous
//
#include <hip/hip_runtime.h>
#include <cstdint>
#include <cstddef>

// ---------------------------------------------------------------------------
// AttnBlock, 4 dispatches, every GEMM grid = exactly one resident round:
//   prep(512thr): W2=wp.wv + bpv + rowsum=0 (0-127); WqkT=rsK*wk^T.wq + cu
//                 (128-255); GN TRUE single-pass -> hT (256-767; chans split
//                 across thread halves, no re-read)
//   tmp|vP: tmp[16384][512] = hT.WqkT^T + cu   (256 BM256 tiles)
//           vP[b][co][j] = W2.hT + bpv          (256 BM256 tiles, csplit)
//   scores: E[b][i][j] = exp(tmp_i . hT_j); rowsum atomic (512 BM256)
//   PV':    out[(b,c)][i] = x + bp[c] + (sum_j vP.E)/rowsum (512 BM128)
// Algebra: S = q.k -> hT.(wq^T wk).hT^T + (wk^T bq).hT_j + [i-only + const];
// i-only/const cancel in softmax (shift invariance). W2 = wp.wv absorbs v
// and proj. rsK folded into WqkT/cu.
// Pinned lessons: BM256 (256,3) spills (R10); grids = 1 resident round (R12);
// wave-uniform K-loop global reads serialize as s_loads -> LDS-stage (R13);
// GN float4-vectorized (R14); 8-phase loses at K=512 (R16); flash-fusing
// scores+PV blocked at head-dim 512 (O-tile exceeds reg/LDS budget).
// ---------------------------------------------------------------------------

typedef __bf16 bf16x8 __attribute__((ext_vector_type(8)));
typedef float f32x4 __attribute__((ext_vector_type(4)));

typedef __attribute__((address_space(1))) const void gl_void;
typedef __attribute__((address_space(3))) void lds_void;

#define GLD16(g, l)                                                     \
  __builtin_amdgcn_global_load_lds((gl_void*)(uintptr_t)(g),            \
                                   (lds_void*)(uintptr_t)(l), 16, 0, 0)

__device__ __forceinline__ unsigned short f2bf(float f) {
  unsigned int u = __builtin_bit_cast(unsigned int, f);
  u += 0x7fffu + ((u >> 16) & 1u);  // round-to-nearest-even
  return (unsigned short)(u >> 16);
}
__device__ __forceinline__ float bf2f(unsigned int h) {
  return __builtin_bit_cast(float, h << 16);
}

// ---- prep (512 thr): W2 (0-127) + WqkT/cu (128-255) + GN 1-pass (256-767) -
__global__ __launch_bounds__(512) void prep_kernel(
    const float* __restrict__ x, const float* __restrict__ gsc,
    const float* __restrict__ gbi, unsigned short* __restrict__ hT,
    const float* __restrict__ wq, const float* __restrict__ wk,
    const float* __restrict__ wv, const float* __restrict__ wp,
    const float* __restrict__ bq, const float* __restrict__ bv,
    unsigned short* __restrict__ WqkTo, unsigned short* __restrict__ W2o,
    float* __restrict__ cu, float* __restrict__ bpv,
    float* __restrict__ rowsum, float rsK) {
  const int t = threadIdx.x;
  const int wid = t >> 6, lane = t & 63;
  if (blockIdx.x < 128) {  // ---- W2 = wp.wv (fp32), bpv = wp.bv, rowsum=0 ----
    __shared__ float swp[4][512];  // wp rows in LDS (broadcast reads)
    __shared__ float sbv[512];
    __shared__ float redp[4][8];
    const int o0 = blockIdx.x * 4;
#pragma unroll
    for (int r = 0; r < 4; ++r)
      swp[r][t] = wp[(size_t)(o0 + r) * 512 + t];
    sbv[t] = bv[t];
    if (t < 128) rowsum[blockIdx.x * 128 + t] = 0.f;  // 128*128 = 16384
    __syncthreads();
    float a0[4] = {};
    for (int c = 0; c < 512; ++c) {
      const float v0 = wv[(size_t)c * 512 + t];  // coalesced
#pragma unroll
      for (int r = 0; r < 4; ++r) a0[r] = fmaf(swp[r][c], v0, a0[r]);
    }
#pragma unroll
    for (int r = 0; r < 4; ++r)
      W2o[(size_t)(o0 + r) * 512 + t] = f2bf(a0[r]);
    float s[4];
#pragma unroll
    for (int r = 0; r < 4; ++r) s[r] = swp[r][t] * sbv[t];
#pragma unroll
    for (int r = 0; r < 4; ++r)
#pragma unroll
      for (int off = 32; off > 0; off >>= 1) s[r] += __shfl_down(s[r], off);
    if (lane == 0) {
#pragma unroll
      for (int r = 0; r < 4; ++r) redp[r][wid] = s[r];
    }
    __syncthreads();
    if (t == 0) {
#pragma unroll
      for (int r = 0; r < 4; ++r) {
        float acc = 0.f;
#pragma unroll
        for (int w = 0; w < 8; ++w) acc += redp[r][w];
        bpv[o0 + r] = acc;
      }
    }
    return;
  }
  if (blockIdx.x < 256) {  // ---- WqkT[n][c] = rsK*sum_o wk[o][n] wq[o][c] ----
    __shared__ float swk[512][4];  // wk cols n0..n0+3 (staged via float4 rows)
    __shared__ float sbq[512];
    __shared__ float redq[4][8];
    const int n0 = (blockIdx.x - 128) * 4;
    *(float4*)&swk[t][0] = *(const float4*)&wk[(size_t)t * 512 + n0];
    sbq[t] = bq[t];
    __syncthreads();
    float a0[4] = {};
    for (int o = 0; o < 512; ++o) {
      const float q0 = wq[(size_t)o * 512 + t];  // coalesced
#pragma unroll
      for (int r = 0; r < 4; ++r) a0[r] = fmaf(swk[o][r], q0, a0[r]);
    }
#pragma unroll
    for (int r = 0; r < 4; ++r)
      WqkTo[(size_t)(n0 + r) * 512 + t] = f2bf(a0[r] * rsK);
    float s[4];
#pragma unroll
    for (int r = 0; r < 4; ++r) s[r] = swk[t][r] * sbq[t];
#pragma unroll
    for (int r = 0; r < 4; ++r)
#pragma unroll
      for (int off = 32; off > 0; off >>= 1) s[r] += __shfl_down(s[r], off);
    if (lane == 0) {
#pragma unroll
      for (int r = 0; r < 4; ++r) redq[r][wid] = s[r];
    }
    __syncthreads();
    if (t == 0) {
#pragma unroll
      for (int r = 0; r < 4; ++r) {
        float acc = 0.f;
#pragma unroll
        for (int w = 0; w < 8; ++w) acc += redq[r][w];
        cu[n0 + r] = rsK * acc;
      }
    }
    return;
  }
  // ---- GroupNorm, TRUE single pass: thread (col, chalf) owns 8 chans ----
  __shared__ float red[2][8];
  const int gb = blockIdx.x - 256;
  const int b = gb >> 5;
  const int g = gb & 31;
  const int col = t & 255;       // float4 column (rows 4col..4col+3)
  const int chalf = t >> 8;      // 0: chans 0-7, 1: chans 8-15
  const float* xp = x + ((size_t)(b * 512 + g * 16 + chalf * 8)) * 1024;

  float4 r4[8];  // this thread's 8 channels stay live (32 VGPR)
  float s = 0.f, s2 = 0.f;
#pragma unroll
  for (int c = 0; c < 8; ++c) {
    r4[c] = ((const float4*)(xp + (size_t)c * 1024))[col];
    s += (r4[c].x + r4[c].y) + (r4[c].z + r4[c].w);
    s2 += (r4[c].x * r4[c].x + r4[c].y * r4[c].y) +
          (r4[c].z * r4[c].z + r4[c].w * r4[c].w);
  }
#pragma unroll
  for (int off = 32; off > 0; off >>= 1) {
    s += __shfl_down(s, off);
    s2 += __shfl_down(s2, off);
  }
  if (lane == 0) { red[0][wid] = s; red[1][wid] = s2; }
  __syncthreads();
  float S = 0.f, S2 = 0.f;
#pragma unroll
  for (int w = 0; w < 8; ++w) { S += red[0][w]; S2 += red[1][w]; }
  const float mean = S * (1.f / 16384.f);
  const float var = S2 * (1.f / 16384.f) - mean * mean;
  const float rstd = rsqrtf(var + 1e-6f);

  float sc[8], bi[8];
#pragma unroll
  for (int c = 0; c < 8; ++c) {
    sc[c] = gsc[g * 16 + chalf * 8 + c] * rstd;
    bi[c] = gbi[g * 16 + chalf * 8 + c] - mean * sc[c];
  }
  unsigned short* hp = hT + (size_t)b * 1024 * 512 + g * 16 + chalf * 8;
#pragma unroll
  for (int ii = 0; ii < 4; ++ii) {  // float4 component = row 4col+ii
    const int i = 4 * col + ii;
    unsigned int pk[4];
#pragma unroll
    for (int p = 0; p < 4; ++p) {
      float e0, e1;
      if (ii == 0) { e0 = r4[2 * p].x; e1 = r4[2 * p + 1].x; }
      else if (ii == 1) { e0 = r4[2 * p].y; e1 = r4[2 * p + 1].y; }
      else if (ii == 2) { e0 = r4[2 * p].z; e1 = r4[2 * p + 1].z; }
      else { e0 = r4[2 * p].w; e1 = r4[2 * p + 1].w; }
      const float v0 = e0 * sc[2 * p] + bi[2 * p];
      const float v1 = e1 * sc[2 * p + 1] + bi[2 * p + 1];
      pk[p] = (unsigned int)f2bf(v0) | ((unsigned int)f2bf(v1) << 16);
    }
    *(uint4*)(hp + (size_t)i * 512) = make_uint4(pk[0], pk[1], pk[2], pk[3]);
  }
}

// ------------------------- NT GEMM engine ----------------------------------
// D[m][n] = scale * sum_k A[m][k]*Bt[n][k].
// epi 0: plain  (+bias bmode{1:[gm],2:[gn]}, +resid, csplit offset)
// epi 2: exp + atomic rowsum (scores; bf16 out, row-major)
// epi 4: PV': v/rowsum[(m0>>9)*1024+gn] + bias[gm&511] + resid; fp32 row-major
struct GArgs {
  const unsigned short *A, *B;
  void* Out;
  const float *bias, *resid;
  float* rowsum;
  long long sBb, sOb;
  int lda, ldb, ldo, btshift, obf, csplit, K, bmode, nx, nwg, epi;
  float scale;
};

template <int BM>
__global__ __launch_bounds__(256, (BM == 256 ? 2 : 3)) void gemm_nt(
    GArgs g0, GArgs g1, int split) {
  constexpr int MF = BM / 32;      // m-frags per wave (8 / 4)
  constexpr int WMS = BM / 2;      // wave m-span (128 / 64)
  constexpr int ASLABS = BM / 32;  // A staging slabs (8 / 4)
  constexpr int BOFF = BM * 128;   // byte offset of B region in LDS
  __shared__ char lds[BM * 128 + 16384];

  const bool r1 = (int)blockIdx.x >= split;
  const GArgs g = r1 ? g1 : g0;
  const int lid = blockIdx.x - (r1 ? split : 0);

  // XCD-chunked remap within role (nwg % 8 == 0 for all our grids)
  const int cpx = g.nwg >> 3;
  const int rid = (lid & 7) * cpx + (lid >> 3);
  const int bx = rid % g.nx, by = rid / g.nx;
  const int m0 = by * BM, n0 = bx * 128;

  const int t = threadIdx.x;
  const int wid = t >> 6, lane = t & 63;
  const int srow = t >> 3;                        // 32-row slab row
  const int schunk = ((t & 7) ^ (srow & 7)) * 8;  // pre-swizzled src chunk
  const unsigned short* gA = g.A + (size_t)(m0 + srow) * g.lda + schunk;
  const unsigned short* gB =
      g.B + (g.btshift ? (size_t)(m0 >> g.btshift) * g.sBb : 0) +
      (size_t)(n0 + srow) * g.ldb + schunk;
  const int stgO = wid << 10;  // wave-uniform 1KB sub-slab

  f32x4 acc[MF][4] = {};
  const int wm = wid >> 1, wn = wid & 1;
  const int fr = lane & 15;
  const int slot0 = (((lane >> 4) ^ (fr & 7)) << 4);
  const int aoff = (wm * WMS + fr) * 128 + slot0;
  const int boff = BOFF + (wn * 64 + fr) * 128 + slot0;

  const int nt = g.K >> 6;
  for (int tt = 0; tt < nt; ++tt) {
    const size_t ko = (size_t)tt * 64;
#pragma unroll
    for (int c = 0; c < ASLABS; ++c)
      GLD16(gA + ko + (size_t)(c * 32) * g.lda, lds + c * 4096 + stgO);
#pragma unroll
    for (int c = 0; c < 4; ++c)
      GLD16(gB + ko + (size_t)(c * 32) * g.ldb, lds + BOFF + c * 4096 + stgO);
    __syncthreads();  // drains vmcnt -> tile visible to all waves
#pragma unroll
    for (int kk = 0; kk < 2; ++kk) {
      const int kx = kk ? 64 : 0;  // second k-half: chunk slot ^= 4
      bf16x8 av[MF], bv[4];
#pragma unroll
      for (int mf = 0; mf < MF; ++mf)
        av[mf] = *(const bf16x8*)(lds + ((aoff + mf * 2048) ^ kx));
#pragma unroll
      for (int nf = 0; nf < 4; ++nf)
        bv[nf] = *(const bf16x8*)(lds + ((boff + nf * 2048) ^ kx));
      __builtin_amdgcn_s_setprio(1);
#pragma unroll
      for (int mf = 0; mf < MF; ++mf)
#pragma unroll
        for (int nf = 0; nf < 4; ++nf)
          acc[mf][nf] = __builtin_amdgcn_mfma_f32_16x16x32_bf16(
              av[mf], bv[nf], acc[mf][nf], 0, 0, 0);
      __builtin_amdgcn_s_setprio(0);
    }
    __syncthreads();  // protect LDS before next stage
  }

  const int em = m0 + wm * WMS + (lane >> 4) * 4;
  const int en = n0 + wn * 64 + fr;

  float rdiv[4];
  if (g.epi == 4) {
    const int rbase = (m0 >> 9) << 10;  // batch = m0>>9, E-row base
#pragma unroll
    for (int nf = 0; nf < 4; ++nf)
      rdiv[nf] = 1.f / g.rowsum[rbase + en + nf * 16];
  }

#pragma unroll
  for (int mf = 0; mf < MF; ++mf) {
#pragma unroll
    for (int r = 0; r < 4; ++r) {
      const int gm = em + mf * 16 + r;
      if (g.epi == 2) {  // scores: exp, atomic row sum of ROUNDED values
        float rsum = 0.f;
#pragma unroll
        for (int nf = 0; nf < 4; ++nf) {
          const int gn = en + nf * 16;
          unsigned short h = f2bf(__expf(acc[mf][nf][r] * g.scale));
          rsum += bf2f(h);
          ((unsigned short*)g.Out)[(size_t)gm * g.ldo + gn] = h;
        }
        rsum += __shfl_xor(rsum, 1);
        rsum += __shfl_xor(rsum, 2);
        rsum += __shfl_xor(rsum, 4);
        rsum += __shfl_xor(rsum, 8);
        if ((lane & 15) == 0) atomicAdd(&g.rowsum[gm], rsum);
        continue;
      }
      if (g.epi == 4) {  // PV': normalize + bias + resid, fp32 row-major
        const float bb = g.bias[gm & 511];
#pragma unroll
        for (int nf = 0; nf < 4; ++nf) {
          const int gn = en + nf * 16;
          const size_t off = (size_t)gm * g.ldo + gn;
          ((float*)g.Out)[off] = acc[mf][nf][r] * rdiv[nf] + bb + g.resid[off];
        }
        continue;
      }
#pragma unroll
      for (int nf = 0; nf < 4; ++nf) {
        const int gn = en + nf * 16;
        float v = acc[mf][nf][r] * g.scale;
        if (g.bmode == 1) v += g.bias[gm];
        else if (g.bmode == 2) v += g.bias[gn];
        size_t off;
        if (g.csplit)
          off = (size_t)(gn >> 10) * g.sOb + (size_t)gm * g.ldo + (gn & 1023);
        else
          off = (size_t)gm * g.ldo + gn;
        if (g.resid) v += g.resid[off];
        if (g.obf) ((unsigned short*)g.Out)[off] = f2bf(v);
        else ((float*)g.Out)[off] = v;
      }
    }
  }
}

// ---------------------------------------------------------------------------
extern "C" void kernel_launch(void* const* d_in, const int* in_sizes, int n_in,
                              void* d_out, int out_size, void* d_ws,
                              size_t ws_size, hipStream_t stream) {
  const float* x   = (const float*)d_in[0];
  const float* gsc = (const float*)d_in[1];
  const float* gbi = (const float*)d_in[2];
  const float* wq  = (const float*)d_in[3];
  const float* bq  = (const float*)d_in[4];
  const float* wk  = (const float*)d_in[5];
  const float* wv  = (const float*)d_in[7];
  const float* bv  = (const float*)d_in[8];
  const float* wp  = (const float*)d_in[9];
  const float* bp  = (const float*)d_in[10];
  float* out = (float*)d_out;

  char* ws = (char*)d_ws;
  const size_t MB = 1024ull * 1024ull;
  unsigned short* hT   = (unsigned short*)(ws);             // 16MB [16384][512]
  unsigned short* tmpB = (unsigned short*)(ws + 16 * MB);   // 16MB [16384][512]
  unsigned short* E    = (unsigned short*)(ws + 48 * MB);   // 32MB [16384][1024]
  unsigned short* vP   = (unsigned short*)(ws + 80 * MB);   // 16MB [16][512][1024]
  unsigned short* WqkT = (unsigned short*)(ws + 96 * MB);   // 0.5MB [512][512]
  unsigned short* W2   = (unsigned short*)(ws + 98 * MB);   // 0.5MB [512][512]
  float*          cu   = (float*)(ws + 99 * MB);            // 2KB
  float*          bpv  = (float*)(ws + 99 * MB + 8 * 1024); // 2KB
  float*          rowsum = (float*)(ws + 99 * MB + 16 * 1024);  // 64KB

  const float rsK = 0.04419417382415922f;  // 512^-0.5

  prep_kernel<<<768, 512, 0, stream>>>(x, gsc, gbi, hT, wq, wk, wv, wp,
                                       bq, bv, WqkT, W2, cu, bpv, rowsum,
                                       rsK);

  // tmp[m][n] = sum_c hT[m][c] WqkT[n][c] + cu[n]   (rsK pre-folded)
  GArgs tg{hT, WqkT, tmpB, cu, nullptr, nullptr, 0, 0,
           512, 512, 512, 0, 1, 0, 512, 2, 4, 256, 0, 1.f};
  // vP[b][co][j] = sum_c W2[co][c] hT[(b,j)][c] + bpv[co]  (csplit writes)
  GArgs vp{W2, hT, vP, bpv, nullptr, nullptr, 0, 524288,
           512, 512, 1024, 0, 1, 1, 512, 1, 128, 256, 0, 1.f};
  // scores: E[m][j] = exp(tmp_m . hT_{b,j}); rowsum atomic. b = m>>10.
  GArgs sc{tmpB, hT, E, nullptr, nullptr, rowsum, 524288, 0,
           512, 512, 1024, 10, 1, 0, 512, 0, 8, 512, 2, 1.f};
  // PV': out[(b,c)][i] = x + bp[c] + (sum_j vP[(b,c)][j] E[b][i][j])/rowsum
  GArgs pv{vP, E, out, bp, x, rowsum, 1048576, 0,
           1024, 1024, 1024, 9, 0, 0, 1024, 0, 8, 512, 4, 1.f};

  gemm_nt<256><<<512, 256, 0, stream>>>(tg, vp, 256);  // tmp || vP, 1 round
  gemm_nt<256><<<512, 256, 0, stream>>>(sc, sc, 512);
  gemm_nt<128><<<512, 256, 0, stream>>>(pv, pv, 512);
}

// Round 20
// 141.892 us; speedup vs baseline: 1.3523x; 1.0992x over previous
//
#include <hip/hip_runtime.h>
#include <cstdint>
#include <cstddef>

// ---------------------------------------------------------------------------
// AttnBlock, 4 dispatches, every GEMM grid = exactly one resident round:
//   prep(512thr): W2=wp.wv + bpv + rowsum=0; WqkT=rsK*wk^T.wq + cu;
//                 GN true single-pass -> hT
//   tmp|vP: gemm512 (256+256 blocks)   tmp = hT.WqkT^T + cu ; vP = W2.hT + bpv
//   scores: gemm512 (512 blocks)       E = exp(tmp.hT^T) + atomic rowsum
//   PV':    gemm_nt<128> (512 blocks)  out = x + bp + vP.E^T / rowsum
// gemm512 = BM256xBN128, 512 thr = 8 waves (4m x 2n), per-wave 64x64
// (acc[4][4] = 64 VGPR -> ~108 total -> 4 waves/SIMD -> 2 blocks/CU =
// 16 waves/CU, 2x the 256-thr engine's TLP). Same 2-barrier loop, chunk-XOR
// swizzle, GLD16 staging (4 A-slabs + 2 B-slabs of 64 rows).
// Algebra: qk eliminated via softmax shift-invariance (WqkT = rsK*wk^T.wq,
// j-only term cu = rsK*wk^T.bq); v/proj folded into W2 = wp.wv.
// Pinned: BM256 4-wave (256,3) spills (R10); grids = 1 round (R12);
// wave-uniform K-loop reads -> LDS-stage (R13); 8-phase loses at K=512 (R16);
// flash fusion blocked at head-dim 512.
// ---------------------------------------------------------------------------

typedef __bf16 bf16x8 __attribute__((ext_vector_type(8)));
typedef float f32x4 __attribute__((ext_vector_type(4)));

typedef __attribute__((address_space(1))) const void gl_void;
typedef __attribute__((address_space(3))) void lds_void;

#define GLD16(g, l)                                                     \
  __builtin_amdgcn_global_load_lds((gl_void*)(uintptr_t)(g),            \
                                   (lds_void*)(uintptr_t)(l), 16, 0, 0)

__device__ __forceinline__ unsigned short f2bf(float f) {
  unsigned int u = __builtin_bit_cast(unsigned int, f);
  u += 0x7fffu + ((u >> 16) & 1u);  // round-to-nearest-even
  return (unsigned short)(u >> 16);
}
__device__ __forceinline__ float bf2f(unsigned int h) {
  return __builtin_bit_cast(float, h << 16);
}

// ---- prep (512 thr): W2 (0-127) + WqkT/cu (128-255) + GN 1-pass (256-767) -
__global__ __launch_bounds__(512) void prep_kernel(
    const float* __restrict__ x, const float* __restrict__ gsc,
    const float* __restrict__ gbi, unsigned short* __restrict__ hT,
    const float* __restrict__ wq, const float* __restrict__ wk,
    const float* __restrict__ wv, const float* __restrict__ wp,
    const float* __restrict__ bq, const float* __restrict__ bv,
    unsigned short* __restrict__ WqkTo, unsigned short* __restrict__ W2o,
    float* __restrict__ cu, float* __restrict__ bpv,
    float* __restrict__ rowsum, float rsK) {
  const int t = threadIdx.x;
  const int wid = t >> 6, lane = t & 63;
  if (blockIdx.x < 128) {  // ---- W2 = wp.wv (fp32), bpv = wp.bv, rowsum=0 ----
    __shared__ float swp[4][512];
    __shared__ float sbv[512];
    __shared__ float redp[4][8];
    const int o0 = blockIdx.x * 4;
#pragma unroll
    for (int r = 0; r < 4; ++r)
      swp[r][t] = wp[(size_t)(o0 + r) * 512 + t];
    sbv[t] = bv[t];
    if (t < 128) rowsum[blockIdx.x * 128 + t] = 0.f;
    __syncthreads();
    float a0[4] = {};
    for (int c = 0; c < 512; ++c) {
      const float v0 = wv[(size_t)c * 512 + t];
#pragma unroll
      for (int r = 0; r < 4; ++r) a0[r] = fmaf(swp[r][c], v0, a0[r]);
    }
#pragma unroll
    for (int r = 0; r < 4; ++r)
      W2o[(size_t)(o0 + r) * 512 + t] = f2bf(a0[r]);
    float s[4];
#pragma unroll
    for (int r = 0; r < 4; ++r) s[r] = swp[r][t] * sbv[t];
#pragma unroll
    for (int r = 0; r < 4; ++r)
#pragma unroll
      for (int off = 32; off > 0; off >>= 1) s[r] += __shfl_down(s[r], off);
    if (lane == 0) {
#pragma unroll
      for (int r = 0; r < 4; ++r) redp[r][wid] = s[r];
    }
    __syncthreads();
    if (t == 0) {
#pragma unroll
      for (int r = 0; r < 4; ++r) {
        float acc = 0.f;
#pragma unroll
        for (int w = 0; w < 8; ++w) acc += redp[r][w];
        bpv[o0 + r] = acc;
      }
    }
    return;
  }
  if (blockIdx.x < 256) {  // ---- WqkT[n][c] = rsK*sum_o wk[o][n] wq[o][c] ----
    __shared__ float swk[512][4];
    __shared__ float sbq[512];
    __shared__ float redq[4][8];
    const int n0 = (blockIdx.x - 128) * 4;
    *(float4*)&swk[t][0] = *(const float4*)&wk[(size_t)t * 512 + n0];
    sbq[t] = bq[t];
    __syncthreads();
    float a0[4] = {};
    for (int o = 0; o < 512; ++o) {
      const float q0 = wq[(size_t)o * 512 + t];
#pragma unroll
      for (int r = 0; r < 4; ++r) a0[r] = fmaf(swk[o][r], q0, a0[r]);
    }
#pragma unroll
    for (int r = 0; r < 4; ++r)
      WqkTo[(size_t)(n0 + r) * 512 + t] = f2bf(a0[r] * rsK);
    float s[4];
#pragma unroll
    for (int r = 0; r < 4; ++r) s[r] = swk[t][r] * sbq[t];
#pragma unroll
    for (int r = 0; r < 4; ++r)
#pragma unroll
      for (int off = 32; off > 0; off >>= 1) s[r] += __shfl_down(s[r], off);
    if (lane == 0) {
#pragma unroll
      for (int r = 0; r < 4; ++r) redq[r][wid] = s[r];
    }
    __syncthreads();
    if (t == 0) {
#pragma unroll
      for (int r = 0; r < 4; ++r) {
        float acc = 0.f;
#pragma unroll
        for (int w = 0; w < 8; ++w) acc += redq[r][w];
        cu[n0 + r] = rsK * acc;
      }
    }
    return;
  }
  // ---- GroupNorm, single pass: thread (col, chalf) owns 8 chans ----
  __shared__ float red[2][8];
  const int gb = blockIdx.x - 256;
  const int b = gb >> 5;
  const int g = gb & 31;
  const int col = t & 255;
  const int chalf = t >> 8;
  const float* xp = x + ((size_t)(b * 512 + g * 16 + chalf * 8)) * 1024;

  float4 r4[8];
  float s = 0.f, s2 = 0.f;
#pragma unroll
  for (int c = 0; c < 8; ++c) {
    r4[c] = ((const float4*)(xp + (size_t)c * 1024))[col];
    s += (r4[c].x + r4[c].y) + (r4[c].z + r4[c].w);
    s2 += (r4[c].x * r4[c].x + r4[c].y * r4[c].y) +
          (r4[c].z * r4[c].z + r4[c].w * r4[c].w);
  }
#pragma unroll
  for (int off = 32; off > 0; off >>= 1) {
    s += __shfl_down(s, off);
    s2 += __shfl_down(s2, off);
  }
  if (lane == 0) { red[0][wid] = s; red[1][wid] = s2; }
  __syncthreads();
  float S = 0.f, S2 = 0.f;
#pragma unroll
  for (int w = 0; w < 8; ++w) { S += red[0][w]; S2 += red[1][w]; }
  const float mean = S * (1.f / 16384.f);
  const float var = S2 * (1.f / 16384.f) - mean * mean;
  const float rstd = rsqrtf(var + 1e-6f);

  float sc[8], bi[8];
#pragma unroll
  for (int c = 0; c < 8; ++c) {
    sc[c] = gsc[g * 16 + chalf * 8 + c] * rstd;
    bi[c] = gbi[g * 16 + chalf * 8 + c] - mean * sc[c];
  }
  unsigned short* hp = hT + (size_t)b * 1024 * 512 + g * 16 + chalf * 8;
#pragma unroll
  for (int ii = 0; ii < 4; ++ii) {
    const int i = 4 * col + ii;
    unsigned int pk[4];
#pragma unroll
    for (int p = 0; p < 4; ++p) {
      float e0, e1;
      if (ii == 0) { e0 = r4[2 * p].x; e1 = r4[2 * p + 1].x; }
      else if (ii == 1) { e0 = r4[2 * p].y; e1 = r4[2 * p + 1].y; }
      else if (ii == 2) { e0 = r4[2 * p].z; e1 = r4[2 * p + 1].z; }
      else { e0 = r4[2 * p].w; e1 = r4[2 * p + 1].w; }
      const float v0 = e0 * sc[2 * p] + bi[2 * p];
      const float v1 = e1 * sc[2 * p + 1] + bi[2 * p + 1];
      pk[p] = (unsigned int)f2bf(v0) | ((unsigned int)f2bf(v1) << 16);
    }
    *(uint4*)(hp + (size_t)i * 512) = make_uint4(pk[0], pk[1], pk[2], pk[3]);
  }
}

// ------------------------- GEMM argument block -----------------------------
struct GArgs {
  const unsigned short *A, *B;
  void* Out;
  const float *bias, *resid;
  float* rowsum;
  long long sBb, sOb;
  int lda, ldb, ldo, btshift, obf, csplit, K, bmode, nx, nwg, epi;
  float scale;
};

// Shared epilogue (per-wave 64x64 tile, MF=4), used by both engines.
__device__ __forceinline__ void epilogue4(
    const GArgs& g, f32x4 acc[4][4], int em, int en, int lane) {
  float rdiv[4];
  if (g.epi == 4) {
    const int rbase = ((em >> 9) << 10);  // batch = row>>9 (rows in-batch)
#pragma unroll
    for (int nf = 0; nf < 4; ++nf)
      rdiv[nf] = 1.f / g.rowsum[rbase + en + nf * 16];
  }
#pragma unroll
  for (int mf = 0; mf < 4; ++mf) {
#pragma unroll
    for (int r = 0; r < 4; ++r) {
      const int gm = em + mf * 16 + r;
      if (g.epi == 2) {  // scores: exp, atomic row sum of ROUNDED values
        float rsum = 0.f;
#pragma unroll
        for (int nf = 0; nf < 4; ++nf) {
          const int gn = en + nf * 16;
          unsigned short h = f2bf(__expf(acc[mf][nf][r] * g.scale));
          rsum += bf2f(h);
          ((unsigned short*)g.Out)[(size_t)gm * g.ldo + gn] = h;
        }
        rsum += __shfl_xor(rsum, 1);
        rsum += __shfl_xor(rsum, 2);
        rsum += __shfl_xor(rsum, 4);
        rsum += __shfl_xor(rsum, 8);
        if ((lane & 15) == 0) atomicAdd(&g.rowsum[gm], rsum);
        continue;
      }
      if (g.epi == 4) {  // PV': normalize + bias + resid, fp32 row-major
        const float bb = g.bias[gm & 511];
#pragma unroll
        for (int nf = 0; nf < 4; ++nf) {
          const int gn = en + nf * 16;
          const size_t off = (size_t)gm * g.ldo + gn;
          ((float*)g.Out)[off] = acc[mf][nf][r] * rdiv[nf] + bb + g.resid[off];
        }
        continue;
      }
#pragma unroll
      for (int nf = 0; nf < 4; ++nf) {
        const int gn = en + nf * 16;
        float v = acc[mf][nf][r] * g.scale;
        if (g.bmode == 1) v += g.bias[gm];
        else if (g.bmode == 2) v += g.bias[gn];
        size_t off;
        if (g.csplit)
          off = (size_t)(gn >> 10) * g.sOb + (size_t)gm * g.ldo + (gn & 1023);
        else
          off = (size_t)gm * g.ldo + gn;
        if (g.resid) v += g.resid[off];
        if (g.obf) ((unsigned short*)g.Out)[off] = f2bf(v);
        else ((float*)g.Out)[off] = v;
      }
    }
  }
}

// -------- gemm512: BM256 x BN128, 512 thr = 8 waves (4m x 2n) --------------
// Per-wave 64x64 (acc[4][4]); 48KB single-buffer LDS; 2-barrier K-loop;
// ~108 VGPR -> 4 waves/SIMD -> 2 blocks/CU = 16 waves/CU.
__global__ __launch_bounds__(512) void gemm512(GArgs g0, GArgs g1, int split) {
  __shared__ char lds[49152];  // A 32KB @0, B 16KB @32768

  const bool r1 = (int)blockIdx.x >= split;
  const GArgs g = r1 ? g1 : g0;
  const int lid = blockIdx.x - (r1 ? split : 0);

  const int cpx = g.nwg >> 3;
  const int rid = (lid & 7) * cpx + (lid >> 3);
  const int bx = rid % g.nx, by = rid / g.nx;
  const int m0 = by * 256, n0 = bx * 128;

  const int t = threadIdx.x;  // 0..511
  const int wid = t >> 6, lane = t & 63;
  const int srow = t >> 3;                        // 0..63 (64-row slabs)
  const int schunk = ((t & 7) ^ (srow & 7)) * 8;  // pre-swizzled src chunk
  const unsigned short* gA = g.A + (size_t)(m0 + srow) * g.lda + schunk;
  const unsigned short* gB =
      g.B + (g.btshift ? (size_t)(m0 >> g.btshift) * g.sBb : 0) +
      (size_t)(n0 + srow) * g.ldb + schunk;
  const int stgO = wid << 10;  // 8 waves x 1KB = one 64-row slab (8KB)

  f32x4 acc[4][4] = {};
  const int wm = wid >> 1, wn = wid & 1;  // 4m x 2n waves of 64x64
  const int fr = lane & 15;
  const int slot0 = (((lane >> 4) ^ (fr & 7)) << 4);
  const int aoff = (wm * 64 + fr) * 128 + slot0;
  const int boff = 32768 + (wn * 64 + fr) * 128 + slot0;

  const int nt = g.K >> 6;
  for (int tt = 0; tt < nt; ++tt) {
    const size_t ko = (size_t)tt * 64;
#pragma unroll
    for (int c = 0; c < 4; ++c)
      GLD16(gA + ko + (size_t)(c * 64) * g.lda, lds + c * 8192 + stgO);
#pragma unroll
    for (int c = 0; c < 2; ++c)
      GLD16(gB + ko + (size_t)(c * 64) * g.ldb, lds + 32768 + c * 8192 + stgO);
    __syncthreads();  // drains vmcnt -> tile visible
#pragma unroll
    for (int kk = 0; kk < 2; ++kk) {
      const int kx = kk ? 64 : 0;
      bf16x8 av[4], bv[4];
#pragma unroll
      for (int mf = 0; mf < 4; ++mf)
        av[mf] = *(const bf16x8*)(lds + ((aoff + mf * 2048) ^ kx));
#pragma unroll
      for (int nf = 0; nf < 4; ++nf)
        bv[nf] = *(const bf16x8*)(lds + ((boff + nf * 2048) ^ kx));
      __builtin_amdgcn_s_setprio(1);
#pragma unroll
      for (int mf = 0; mf < 4; ++mf)
#pragma unroll
        for (int nf = 0; nf < 4; ++nf)
          acc[mf][nf] = __builtin_amdgcn_mfma_f32_16x16x32_bf16(
              av[mf], bv[nf], acc[mf][nf], 0, 0, 0);
      __builtin_amdgcn_s_setprio(0);
    }
    __syncthreads();
  }

  const int em = m0 + wm * 64 + (lane >> 4) * 4;
  const int en = n0 + wn * 64 + fr;
  epilogue4(g, acc, em, en, lane);
}

// ------------- gemm_nt<128>: 256 thr, 4 waves (2x2 of 64x64) ---------------
__global__ __launch_bounds__(256, 3) void gemm128(GArgs g0, GArgs g1,
                                                  int split) {
  __shared__ char lds[128 * 128 + 16384];  // A 16KB + B 16KB

  const bool r1 = (int)blockIdx.x >= split;
  const GArgs g = r1 ? g1 : g0;
  const int lid = blockIdx.x - (r1 ? split : 0);

  const int cpx = g.nwg >> 3;
  const int rid = (lid & 7) * cpx + (lid >> 3);
  const int bx = rid % g.nx, by = rid / g.nx;
  const int m0 = by * 128, n0 = bx * 128;

  const int t = threadIdx.x;
  const int wid = t >> 6, lane = t & 63;
  const int srow = t >> 3;
  const int schunk = ((t & 7) ^ (srow & 7)) * 8;
  const unsigned short* gA = g.A + (size_t)(m0 + srow) * g.lda + schunk;
  const unsigned short* gB =
      g.B + (g.btshift ? (size_t)(m0 >> g.btshift) * g.sBb : 0) +
      (size_t)(n0 + srow) * g.ldb + schunk;
  const int stgO = wid << 10;

  f32x4 acc[4][4] = {};
  const int wm = wid >> 1, wn = wid & 1;
  const int fr = lane & 15;
  const int slot0 = (((lane >> 4) ^ (fr & 7)) << 4);
  const int aoff = (wm * 64 + fr) * 128 + slot0;
  const int boff = 16384 + (wn * 64 + fr) * 128 + slot0;

  const int nt = g.K >> 6;
  for (int tt = 0; tt < nt; ++tt) {
    const size_t ko = (size_t)tt * 64;
#pragma unroll
    for (int c = 0; c < 4; ++c)
      GLD16(gA + ko + (size_t)(c * 32) * g.lda, lds + c * 4096 + stgO);
#pragma unroll
    for (int c = 0; c < 4; ++c)
      GLD16(gB + ko + (size_t)(c * 32) * g.ldb, lds + 16384 + c * 4096 + stgO);
    __syncthreads();
#pragma unroll
    for (int kk = 0; kk < 2; ++kk) {
      const int kx = kk ? 64 : 0;
      bf16x8 av[4], bv[4];
#pragma unroll
      for (int mf = 0; mf < 4; ++mf)
        av[mf] = *(const bf16x8*)(lds + ((aoff + mf * 2048) ^ kx));
#pragma unroll
      for (int nf = 0; nf < 4; ++nf)
        bv[nf] = *(const bf16x8*)(lds + ((boff + nf * 2048) ^ kx));
      __builtin_amdgcn_s_setprio(1);
#pragma unroll
      for (int mf = 0; mf < 4; ++mf)
#pragma unroll
        for (int nf = 0; nf < 4; ++nf)
          acc[mf][nf] = __builtin_amdgcn_mfma_f32_16x16x32_bf16(
              av[mf], bv[nf], acc[mf][nf], 0, 0, 0);
      __builtin_amdgcn_s_setprio(0);
    }
    __syncthreads();
  }

  const int em = m0 + wm * 64 + (lane >> 4) * 4;
  const int en = n0 + wn * 64 + fr;
  epilogue4(g, acc, em, en, lane);
}

// ---------------------------------------------------------------------------
extern "C" void kernel_launch(void* const* d_in, const int* in_sizes, int n_in,
                              void* d_out, int out_size, void* d_ws,
                              size_t ws_size, hipStream_t stream) {
  const float* x   = (const float*)d_in[0];
  const float* gsc = (const float*)d_in[1];
  const float* gbi = (const float*)d_in[2];
  const float* wq  = (const float*)d_in[3];
  const float* bq  = (const float*)d_in[4];
  const float* wk  = (const float*)d_in[5];
  const float* wv  = (const float*)d_in[7];
  const float* bv  = (const float*)d_in[8];
  const float* wp  = (const float*)d_in[9];
  const float* bp  = (const float*)d_in[10];
  float* out = (float*)d_out;

  char* ws = (char*)d_ws;
  const size_t MB = 1024ull * 1024ull;
  unsigned short* hT   = (unsigned short*)(ws);             // 16MB [16384][512]
  unsigned short* tmpB = (unsigned short*)(ws + 16 * MB);   // 16MB [16384][512]
  unsigned short* E    = (unsigned short*)(ws + 48 * MB);   // 32MB [16384][1024]
  unsigned short* vP   = (unsigned short*)(ws + 80 * MB);   // 16MB [16][512][1024]
  unsigned short* WqkT = (unsigned short*)(ws + 96 * MB);   // 0.5MB [512][512]
  unsigned short* W2   = (unsigned short*)(ws + 98 * MB);   // 0.5MB [512][512]
  float*          cu   = (float*)(ws + 99 * MB);            // 2KB
  float*          bpv  = (float*)(ws + 99 * MB + 8 * 1024); // 2KB
  float*          rowsum = (float*)(ws + 99 * MB + 16 * 1024);  // 64KB

  const float rsK = 0.04419417382415922f;  // 512^-0.5

  prep_kernel<<<768, 512, 0, stream>>>(x, gsc, gbi, hT, wq, wk, wv, wp,
                                       bq, bv, WqkT, W2, cu, bpv, rowsum,
                                       rsK);

  // tmp[m][n] = sum_c hT[m][c] WqkT[n][c] + cu[n]   (rsK pre-folded)
  GArgs tg{hT, WqkT, tmpB, cu, nullptr, nullptr, 0, 0,
           512, 512, 512, 0, 1, 0, 512, 2, 4, 256, 0, 1.f};
  // vP[b][co][j] = sum_c W2[co][c] hT[(b,j)][c] + bpv[co]  (csplit writes)
  GArgs vp{W2, hT, vP, bpv, nullptr, nullptr, 0, 524288,
           512, 512, 1024, 0, 1, 1, 512, 1, 128, 256, 0, 1.f};
  // scores: E[m][j] = exp(tmp_m . hT_{b,j}); rowsum atomic. b = m>>10.
  GArgs sc{tmpB, hT, E, nullptr, nullptr, rowsum, 524288, 0,
           512, 512, 1024, 10, 1, 0, 512, 0, 8, 512, 2, 1.f};
  // PV': out[(b,c)][i] = x + bp[c] + (sum_j vP[(b,c)][j] E[b][i][j])/rowsum
  GArgs pv{vP, E, out, bp, x, rowsum, 1048576, 0,
           1024, 1024, 1024, 9, 0, 0, 1024, 0, 8, 512, 4, 1.f};

  gemm512<<<512, 512, 0, stream>>>(tg, vp, 256);  // tmp || vP, 1 round
  gemm512<<<512, 512, 0, stream>>>(sc, sc, 512);
  gemm128<<<512, 256, 0, stream>>>(pv, pv, 512);
}